// Round 7
// baseline (974.741 us; speedup 1.0000x reference)
//
#include <hip/hip_runtime.h>
#include <hip/hip_bf16.h>

#define N_NODES 400000
#define N_EDGES 1600000
#define N_GRAPHS 16384
#define N_TILES (N_NODES / 16)

#define BSHIFT 11
#define NBKT ((N_NODES + (1 << BSHIFT) - 1) >> BSHIFT)   // 196 row-buckets
#define BIN_CHUNK 4096

typedef __attribute__((ext_vector_type(8))) short bf16x8;
typedef __attribute__((ext_vector_type(4))) float f32x4;

__device__ __forceinline__ float rlane(float x, int k) {
    return __int_as_float(__builtin_amdgcn_readlane(__float_as_int(x), k));
}
__device__ __forceinline__ int rlanei(int x, int k) {
    return __builtin_amdgcn_readlane(x, k);
}

__device__ __forceinline__ short f2bf(float x) {  // RNE float -> bf16 bits
    unsigned u = __float_as_uint(x);
    unsigned r = (u + 0x7fffu + ((u >> 16) & 1u)) >> 16;
    return (short)r;
}
__device__ __forceinline__ float bf2f(short b) {
    return __uint_as_float(((unsigned)(unsigned short)b) << 16);
}

// ---- fused histogram: edge degree + batch counts ----
__global__ void k_hist(const int* __restrict__ rows, const int* __restrict__ batch,
                       int* __restrict__ degcnt, int* __restrict__ gcnt, int E, int N) {
    int t = blockIdx.x * blockDim.x + threadIdx.x;
    if (t < E) atomicAdd(&degcnt[rows[t]], 1);
    if (t < N) atomicAdd(&gcnt[batch[t]], 1);
}

// ---- scan step 1 ----
__global__ void k_scan_blocksum(const int* __restrict__ src, int* __restrict__ bsum, int n) {
    __shared__ int s[256];
    int t = threadIdx.x;
    int idx = blockIdx.x * 256 + t;
    int v = idx < n ? src[idx] : 0;
    s[t] = v; __syncthreads();
    for (int off = 128; off > 0; off >>= 1) {
        if (t < off) s[t] += s[t + off];
        __syncthreads();
    }
    if (t == 0) bsum[blockIdx.x] = s[0];
}

// ---- scan step 2 ----
__global__ void k_scan_single(const int* __restrict__ src, int* __restrict__ dst, int n) {
    __shared__ int s[256];
    __shared__ int carry_s;
    int t = threadIdx.x;
    if (t == 0) carry_s = 0;
    __syncthreads();
    for (int base = 0; base < n; base += 256) {
        int idx = base + t;
        int v = idx < n ? src[idx] : 0;
        s[t] = v; __syncthreads();
        for (int off = 1; off < 256; off <<= 1) {
            int x = (t >= off) ? s[t - off] : 0;
            __syncthreads();
            s[t] += x;
            __syncthreads();
        }
        int incl = s[t];
        int carry = carry_s;
        if (idx < n) dst[idx] = carry + incl - v;
        __syncthreads();
        if (t == 255) carry_s = carry + incl;
        __syncthreads();
    }
}

// ---- scan step 3 ----
__global__ void k_scan_final(const int* __restrict__ src, const int* __restrict__ boffs,
                             int* __restrict__ row_ptr, int* __restrict__ cursor,
                             float* __restrict__ dinv, int* __restrict__ gstart,
                             int* __restrict__ bcur, int n, int N, int E) {
    __shared__ int s[256];
    int t = threadIdx.x;
    int idx = blockIdx.x * 256 + t;
    int v = idx < n ? src[idx] : 0;
    s[t] = v; __syncthreads();
    for (int off = 1; off < 256; off <<= 1) {
        int x = (t >= off) ? s[t - off] : 0;
        __syncthreads();
        s[t] += x;
        __syncthreads();
    }
    if (idx < n) {
        int excl = boffs[blockIdx.x] + s[t] - v;
        if (idx < N) {
            row_ptr[idx] = excl;
            cursor[idx] = excl;
            dinv[idx] = rsqrtf((float)v + 1.0f);
            if ((idx & ((1 << BSHIFT) - 1)) == 0) bcur[idx >> BSHIFT] = excl;
        } else {
            if (idx == N) row_ptr[N] = E;
            gstart[idx - N] = excl - E;
        }
    }
}

// ---- scatter phase A: bin edges by row-bucket ----
__global__ __launch_bounds__(256) void k_bin(const int* __restrict__ rows,
                                             const int* __restrict__ cols,
                                             int* __restrict__ bcur,
                                             int2* __restrict__ tmp, int E) {
    __shared__ int lcnt[NBKT];
    __shared__ int lbase[NBKT];
    const int t = threadIdx.x;
    const int e0 = blockIdx.x * BIN_CHUNK;
    for (int i = t; i < NBKT; i += 256) lcnt[i] = 0;
    __syncthreads();
    int r[16];
#pragma unroll
    for (int k = 0; k < 16; ++k) {
        int e = e0 + k * 256 + t;
        r[k] = (e < E) ? rows[e] : -1;
        if (r[k] >= 0) atomicAdd(&lcnt[r[k] >> BSHIFT], 1);
    }
    __syncthreads();
    for (int i = t; i < NBKT; i += 256) lbase[i] = atomicAdd(&bcur[i], lcnt[i]);
    __syncthreads();
    for (int i = t; i < NBKT; i += 256) lcnt[i] = 0;
    __syncthreads();
#pragma unroll
    for (int k = 0; k < 16; ++k) {
        int e = e0 + k * 256 + t;
        if (r[k] >= 0) {
            int b = r[k] >> BSHIFT;
            int p = lbase[b] + atomicAdd(&lcnt[b], 1);
            tmp[p] = make_int2(r[k], cols[e]);
        }
    }
}

// ---- scatter phase B ----
__global__ __launch_bounds__(256) void k_scat2(const int2* __restrict__ tmp,
                                               const int* __restrict__ row_ptr,
                                               int* __restrict__ cursor,
                                               int* __restrict__ colsOut, int N) {
    const int b = blockIdx.x;
    const int s = row_ptr[b << BSHIFT];
    const int endr = min((b + 1) << BSHIFT, N);
    const int tend = row_ptr[endr];
#pragma unroll 4
    for (int e = s + threadIdx.x; e < tend; e += 256) {
        int2 rc = tmp[e];
        int pos = atomicAdd(&cursor[rc.x], 1);
        colsOut[pos] = rc.y;
    }
}

// ==== fused GCN layer: aggregate (gather) + MFMA GEMM + epilogue ====
// MODE 0: layer 1  — in = x (unscaled, IN_D=32), per-edge dj scaling,
//                    epilogue writes h' = dinv * relu(z)
// MODE 1: layer 2  — in = h' (pre-scaled), epilogue writes h' = dinv * relu(z)
// MODE 2: layer 3  — in = h' (pre-scaled), epilogue pools relu(z) per graph
//                    via atomics (psum / pmax); h3 never hits HBM.
template <int IN_D, int MODE>
__global__ __launch_bounds__(256) void k_fused(
        const float* __restrict__ in, const float* __restrict__ W,
        const float* __restrict__ bias, const int* __restrict__ row_ptr,
        const int* __restrict__ cols, const float* __restrict__ dinv,
        const int* __restrict__ batch, float* __restrict__ out,
        float* __restrict__ psum, float* __restrict__ pmax, int nTiles) {
    constexpr int KT = IN_D / 32;
    constexpr int AS = (IN_D == 32) ? 36 : 68;   // padded LDS stride (16B-aligned)
    __shared__ float a_s[4][16][AS];
    const int lane = threadIdx.x & 63;
    const int w = threadIdx.x >> 6;
    const int m = lane & 15;
    const int q = lane >> 4;

    // B-fragments (split-bf16 hi/lo), built once per wave
    bf16x8 Bhi[4][KT], Blo[4][KT];
#pragma unroll
    for (int nt = 0; nt < 4; ++nt) {
#pragma unroll
        for (int kt = 0; kt < KT; ++kt) {
#pragma unroll
            for (int j = 0; j < 8; ++j) {
                int k = kt * 32 + q * 8 + j;
                float ww = W[k * 64 + nt * 16 + m];
                short hi = f2bf(ww);
                Bhi[nt][kt][j] = hi;
                Blo[nt][kt][j] = f2bf(ww - bf2f(hi));
            }
        }
    }
    float br[4];
#pragma unroll
    for (int nt = 0; nt < 4; ++nt) br[nt] = bias[nt * 16 + m];

    const int wid0 = (blockIdx.x * 256 + threadIdx.x) >> 6;
    const int nwv = (gridDim.x * 256) >> 6;

    for (int tile = wid0; tile < nTiles; tile += nwv) {
        const int node0 = tile * 16;
        const int rpv = row_ptr[node0 + min(lane, 16)];
        const float dv16 = dinv[node0 + min(lane, 15)];

        // ---- phase 1: aggregate 16 nodes into a_s ----
        for (int i = 0; i < 16; ++i) {
            const int s0 = rlanei(rpv, i);
            const int cnt = rlanei(rpv, i + 1) - s0;
            const float di = rlane(dv16, i);
            if (IN_D == 64) {
                float acc = in[(size_t)(node0 + i) * 64 + lane];  // self (pre-scaled)
                int base = 0;
                while (base < cnt) {
                    int colv = (base + lane < cnt) ? cols[s0 + base + lane] : 0;
                    int mm = min(cnt - base, 64);
                    int e = 0;
                    for (; e + 4 <= mm; e += 4) {
                        int c0 = rlanei(colv, e + 0);
                        int c1 = rlanei(colv, e + 1);
                        int c2 = rlanei(colv, e + 2);
                        int c3 = rlanei(colv, e + 3);
                        float v0 = in[(size_t)c0 * 64 + lane];
                        float v1 = in[(size_t)c1 * 64 + lane];
                        float v2 = in[(size_t)c2 * 64 + lane];
                        float v3 = in[(size_t)c3 * 64 + lane];
                        acc += ((v0 + v1) + (v2 + v3));
                    }
                    for (; e < mm; ++e) {
                        int c = rlanei(colv, e);
                        acc += in[(size_t)c * 64 + lane];
                    }
                    base += 64;
                }
                a_s[w][i][lane] = di * acc;
            } else {
                // IN_D==32: 64 lanes = 32 channels x 2 edge-slots
                const int ch = lane & 31;
                const int hf = lane >> 5;
                float selfv = in[(size_t)(node0 + i) * 32 + ch];
                float acc = 0.0f;
                int base = 0;
                while (base < cnt) {
                    int colv = (base + lane < cnt) ? cols[s0 + base + lane] : 0;
                    float djv = dinv[colv];
                    int mm = min(cnt - base, 64);
                    int P = (mm + 1) >> 1;
                    int r = 0;
                    for (; r + 4 <= P; r += 4) {
#pragma unroll
                        for (int k2 = 0; k2 < 4; ++k2) {
                            int e = 2 * (r + k2) + hf;
                            int ei = min(e, 63);
                            int cj = __shfl(colv, ei);
                            float wj = __shfl(djv, ei);
                            if (e >= mm) wj = 0.0f;
                            float v = in[(size_t)cj * 32 + ch];
                            acc = fmaf(wj, v, acc);
                        }
                    }
                    for (; r < P; ++r) {
                        int e = 2 * r + hf;
                        int ei = min(e, 63);
                        int cj = __shfl(colv, ei);
                        float wj = __shfl(djv, ei);
                        if (e >= mm) wj = 0.0f;
                        float v = in[(size_t)cj * 32 + ch];
                        acc = fmaf(wj, v, acc);
                    }
                    base += 64;
                }
                acc += __shfl_xor(acc, 32);
                acc = di * fmaf(di, selfv, acc);
                if (lane < 32) a_s[w][i][ch] = acc;
            }
        }

        // ---- phase 2: A-frags from LDS, split-bf16, MFMA ----
        bf16x8 Ahi[KT], Alo[KT];
#pragma unroll
        for (int kt = 0; kt < KT; ++kt) {
            const float* ap = &a_s[w][m][kt * 32 + q * 8];
            f32x4 a0 = *(const f32x4*)ap;
            f32x4 a1 = *(const f32x4*)(ap + 4);
#pragma unroll
            for (int j = 0; j < 4; ++j) {
                short hi = f2bf(a0[j]);
                Ahi[kt][j] = hi;
                Alo[kt][j] = f2bf(a0[j] - bf2f(hi));
            }
#pragma unroll
            for (int j = 0; j < 4; ++j) {
                short hi = f2bf(a1[j]);
                Ahi[kt][4 + j] = hi;
                Alo[kt][4 + j] = f2bf(a1[j] - bf2f(hi));
            }
        }
        f32x4 C[4];
#pragma unroll
        for (int nt = 0; nt < 4; ++nt) C[nt] = (f32x4){0.f, 0.f, 0.f, 0.f};
#pragma unroll
        for (int nt = 0; nt < 4; ++nt) {
#pragma unroll
            for (int kt = 0; kt < KT; ++kt) {
                C[nt] = __builtin_amdgcn_mfma_f32_16x16x32_bf16(Ahi[kt], Bhi[nt][kt], C[nt], 0, 0, 0);
                C[nt] = __builtin_amdgcn_mfma_f32_16x16x32_bf16(Ahi[kt], Blo[nt][kt], C[nt], 0, 0, 0);
                C[nt] = __builtin_amdgcn_mfma_f32_16x16x32_bf16(Alo[kt], Bhi[nt][kt], C[nt], 0, 0, 0);
            }
        }

        // ---- epilogue ----
        if (MODE == 2) {
            // h3 tile -> LDS (reuse a_s), then per-graph-segment pooled atomics
#pragma unroll
            for (int nt = 0; nt < 4; ++nt) {
#pragma unroll
                for (int r = 0; r < 4; ++r) {
                    a_s[w][q * 4 + r][nt * 16 + m] = fmaxf(C[nt][r] + br[nt], 0.0f);
                }
            }
            int bi = batch[node0 + min(lane, 15)];
            int s = 0;
            while (s < 16) {
                int g = rlanei(bi, s);
                int e2 = s + 1;
                while (e2 < 16 && rlanei(bi, e2) == g) ++e2;
                float sum = 0.0f, mx = 0.0f;
                for (int i = s; i < e2; ++i) {
                    float v = a_s[w][i][lane];
                    sum += v;
                    mx = fmaxf(mx, v);
                }
                atomicAdd(&psum[(size_t)g * 64 + lane], sum);
                atomicMax((int*)&pmax[(size_t)g * 64 + lane], __float_as_int(mx));
                s = e2;
            }
        } else {
            float dn[4];
#pragma unroll
            for (int r = 0; r < 4; ++r) dn[r] = dinv[node0 + q * 4 + r];
#pragma unroll
            for (int nt = 0; nt < 4; ++nt) {
#pragma unroll
                for (int r = 0; r < 4; ++r) {
                    float v = dn[r] * fmaxf(C[nt][r] + br[nt], 0.0f);
                    out[(size_t)(node0 + q * 4 + r) * 64 + nt * 16 + m] = v;
                }
            }
        }
    }
}

// ---- assemble fused vector: [mean | max | relu(meta@Wm+bm) | emb | pad] ----
__global__ __launch_bounds__(256) void k_asm(
        const float* __restrict__ psum, const float* __restrict__ pmax,
        const int* __restrict__ gcnt, const float* __restrict__ metadata,
        const int* __restrict__ species, const float* __restrict__ emb,
        const float* __restrict__ Wm, const float* __restrict__ bm,
        float* __restrict__ fused, int G) {
    const int lane = threadIdx.x & 63;
    int wv = (blockIdx.x * blockDim.x + threadIdx.x) >> 6;
    const int nw = (gridDim.x * blockDim.x) >> 6;
    const float bmr = bm[lane];
    float wmr[16];
#pragma unroll
    for (int k = 0; k < 16; ++k) wmr[k] = Wm[k * 64 + lane];
    for (int g = wv; g < G; g += nw) {
        float gc = (float)gcnt[g];
        float mean = psum[(size_t)g * 64 + lane] / fmaxf(gc, 1.0f);
        float mx = pmax[(size_t)g * 64 + lane];
        float md = lane < 16 ? metadata[(size_t)g * 16 + lane] : 0.0f;
        float mval = bmr;
#pragma unroll
        for (int k = 0; k < 16; ++k) mval = fmaf(rlane(md, k), wmr[k], mval);
        mval = fmaxf(mval, 0.0f);
        const int sid = species[g];
        float* fr = fused + (size_t)g * 224;
        fr[lane] = mean;
        fr[64 + lane] = mx;
        fr[128 + lane] = mval;
        if (lane < 16) fr[192 + lane] = emb[(size_t)sid * 16 + lane];
        else if (lane < 32) fr[192 + lane] = 0.0f;
    }
}

// ---- MFMA predictor head: out = relu(fused @ Wp1 + bp1) @ Wp2 + bp2 ----
__global__ __launch_bounds__(256, 2) void k_pred_mfma(
        const float* __restrict__ fused, const float* __restrict__ Wp1,
        const float* __restrict__ bp1, const float* __restrict__ Wp2,
        const float* __restrict__ bp2, float* __restrict__ out, int G) {
    __shared__ __align__(16) short Whi[64 * 232];
    __shared__ __align__(16) short Wlo[64 * 232];
    const int t = threadIdx.x;
    for (int idx = t; idx < 64 * 232; idx += 256) {
        int n = idx / 232;
        int k = idx % 232;
        float w = (k < 208) ? Wp1[(size_t)k * 64 + n] : 0.0f;
        short hi = f2bf(w);
        Whi[n * 232 + k] = hi;
        Wlo[n * 232 + k] = f2bf(w - bf2f(hi));
    }
    __syncthreads();

    const int lane = t & 63;
    const int wave = t >> 6;
    const int m = lane & 15;
    const int q = lane >> 4;
    const int g0 = (blockIdx.x * 4 + wave) * 16;
    if (g0 >= G) return;

    const float* rowp = fused + (size_t)(g0 + m) * 224 + q * 8;

    f32x4 C[4];
#pragma unroll
    for (int nt = 0; nt < 4; ++nt) C[nt] = (f32x4){0.f, 0.f, 0.f, 0.f};

#pragma unroll
    for (int kt = 0; kt < 7; ++kt) {
        f32x4 a0 = *(const f32x4*)(rowp + kt * 32);
        f32x4 a1 = *(const f32x4*)(rowp + kt * 32 + 4);
        bf16x8 Ahi, Alo;
#pragma unroll
        for (int j = 0; j < 4; ++j) {
            short hi = f2bf(a0[j]);
            Ahi[j] = hi;
            Alo[j] = f2bf(a0[j] - bf2f(hi));
        }
#pragma unroll
        for (int j = 0; j < 4; ++j) {
            short hi = f2bf(a1[j]);
            Ahi[4 + j] = hi;
            Alo[4 + j] = f2bf(a1[j] - bf2f(hi));
        }
#pragma unroll
        for (int nt = 0; nt < 4; ++nt) {
            const int boff = (nt * 16 + m) * 232 + kt * 32 + q * 8;
            bf16x8 Bh = *(const bf16x8*)&Whi[boff];
            bf16x8 Bl = *(const bf16x8*)&Wlo[boff];
            C[nt] = __builtin_amdgcn_mfma_f32_16x16x32_bf16(Ahi, Bh, C[nt], 0, 0, 0);
            C[nt] = __builtin_amdgcn_mfma_f32_16x16x32_bf16(Ahi, Bl, C[nt], 0, 0, 0);
            C[nt] = __builtin_amdgcn_mfma_f32_16x16x32_bf16(Alo, Bh, C[nt], 0, 0, 0);
        }
    }

    float wp2r[4], bp1r[4];
#pragma unroll
    for (int nt = 0; nt < 4; ++nt) {
        wp2r[nt] = Wp2[nt * 16 + m];
        bp1r[nt] = bp1[nt * 16 + m];
    }
    const float bp2v = bp2[0];
    float s[4];
#pragma unroll
    for (int r = 0; r < 4; ++r) {
        float acc = 0.0f;
#pragma unroll
        for (int nt = 0; nt < 4; ++nt)
            acc += fmaxf(C[nt][r] + bp1r[nt], 0.0f) * wp2r[nt];
        s[r] = acc;
    }
#pragma unroll
    for (int off = 1; off < 16; off <<= 1) {
#pragma unroll
        for (int r = 0; r < 4; ++r) s[r] += __shfl_xor(s[r], off);
    }
    if (m == 0) {
#pragma unroll
        for (int r = 0; r < 4; ++r) out[g0 + q * 4 + r] = s[r] + bp2v;
    }
}

extern "C" void kernel_launch(void* const* d_in, const int* in_sizes, int n_in,
                              void* d_out, int out_size, void* d_ws, size_t ws_size,
                              hipStream_t stream) {
    const int N = N_NODES, E = N_EDGES, G = N_GRAPHS;
    const int NT = N + G;

    const float* x        = (const float*)d_in[0];
    const float* metadata = (const float*)d_in[1];
    const int*   ei       = (const int*)d_in[2];
    const int*   batch    = (const int*)d_in[3];
    const int*   species  = (const int*)d_in[4];
    const float* W1 = (const float*)d_in[5];
    const float* b1 = (const float*)d_in[6];
    const float* W2 = (const float*)d_in[7];
    const float* b2 = (const float*)d_in[8];
    const float* W3 = (const float*)d_in[9];
    const float* b3 = (const float*)d_in[10];
    const float* Wm = (const float*)d_in[11];
    const float* bm = (const float*)d_in[12];
    const float* emb = (const float*)d_in[13];
    const float* Wp1 = (const float*)d_in[14];
    const float* bp1 = (const float*)d_in[15];
    const float* Wp2 = (const float*)d_in[16];
    const float* bp2 = (const float*)d_in[17];
    float* out = (float*)d_out;

    char* ws = (char*)d_ws;
    size_t off = 0;
    auto alloc = [&](size_t bytes) -> void* {
        void* p = ws + off;
        off = (off + bytes + 255) & ~(size_t)255;
        return p;
    };
    int*   cnt     = (int*)alloc((size_t)NT * 4);
    int*   row_ptr = (int*)alloc((size_t)(N + 1) * 4);
    int*   cursor  = (int*)alloc((size_t)N * 4);
    float* dinv    = (float*)alloc((size_t)N * 4);
    int*   gstart  = (int*)alloc((size_t)G * 4);
    int*   bsum    = (int*)alloc(2048 * 4);
    int*   boffs   = (int*)alloc(2048 * 4);
    int*   bcur    = (int*)alloc((size_t)NBKT * 4);
    int*   colsS   = (int*)alloc((size_t)E * 4);
    float* psum    = (float*)alloc((size_t)G * 64 * 4);
    float* pmax    = (float*)alloc((size_t)G * 64 * 4);
    float* hA      = (float*)alloc((size_t)N * 64 * 4);
    float* hB      = (float*)alloc((size_t)N * 64 * 4);
    float* fused   = (float*)alloc((size_t)G * 224 * 4);

    int* degcnt = cnt;
    int* gcnt = cnt + N;
    int2* tmp = (int2*)hA;        // aliases hA: dead until layer-1 output written

    const int nbE = (E + 255) / 256;    // 6250
    const int nbT = (NT + 255) / 256;   // 1627

    hipMemsetAsync(cnt, 0, (size_t)NT * 4, stream);
    hipMemsetAsync(psum, 0, (size_t)G * 64 * 4, stream);
    hipMemsetAsync(pmax, 0, (size_t)G * 64 * 4, stream);

    k_hist<<<nbE, 256, 0, stream>>>(ei, batch, degcnt, gcnt, E, N);
    k_scan_blocksum<<<nbT, 256, 0, stream>>>(cnt, bsum, NT);
    k_scan_single<<<1, 256, 0, stream>>>(bsum, boffs, nbT);
    k_scan_final<<<nbT, 256, 0, stream>>>(cnt, boffs, row_ptr, cursor, dinv, gstart,
                                          bcur, NT, N, E);
    k_bin<<<(E + BIN_CHUNK - 1) / BIN_CHUNK, 256, 0, stream>>>(ei, ei + E, bcur, tmp, E);
    k_scat2<<<NBKT, 256, 0, stream>>>(tmp, row_ptr, cursor, colsS, N);

    // 3125 blocks x 4 waves = 12500 waves -> exactly 2 tiles/wave
    const int nbF = 3125;
    // layer 1: h1' = Dinv * relu( [Dinv(A+I)Dinv x] @ W1 + b1 )
    k_fused<32, 0><<<nbF, 256, 0, stream>>>(x, W1, b1, row_ptr, colsS, dinv, batch,
                                            hA, psum, pmax, N_TILES);
    // layer 2: h2' = Dinv * relu( [(A'+I') h1'] @ W2 + b2 )
    k_fused<64, 1><<<nbF, 256, 0, stream>>>(hA, W2, b2, row_ptr, colsS, dinv, batch,
                                            hB, psum, pmax, N_TILES);
    // layer 3: pooled sum/max of relu( [(A'+I') h2'] @ W3 + b3 ) via atomics
    k_fused<64, 2><<<nbF, 256, 0, stream>>>(hB, W3, b3, row_ptr, colsS, dinv, batch,
                                            hA, psum, pmax, N_TILES);

    k_asm<<<512, 256, 0, stream>>>(psum, pmax, gcnt, metadata, species, emb, Wm, bm,
                                   fused, G);
    k_pred_mfma<<<(G / 16 + 3) / 4, 256, 0, stream>>>(fused, Wp1, bp1, Wp2, bp2, out, G);
}

// Round 8
// 724.101 us; speedup vs baseline: 1.3461x; 1.3461x over previous
//
#include <hip/hip_runtime.h>
#include <hip/hip_bf16.h>

#define N_NODES 400000
#define N_EDGES 1600000
#define N_GRAPHS 16384

#define BSHIFT 11
#define NBKT ((N_NODES + (1 << BSHIFT) - 1) >> BSHIFT)   // 196 row-buckets
#define BIN_CHUNK 4096

typedef __attribute__((ext_vector_type(8))) short bf16x8;
typedef __attribute__((ext_vector_type(4))) float f32x4;

__device__ __forceinline__ float rlane(float x, int k) {
    return __int_as_float(__builtin_amdgcn_readlane(__float_as_int(x), k));
}
__device__ __forceinline__ int rlanei(int x, int k) {
    return __builtin_amdgcn_readlane(x, k);
}

__device__ __forceinline__ short f2bf(float x) {  // RNE float -> bf16 bits
    unsigned u = __float_as_uint(x);
    unsigned r = (u + 0x7fffu + ((u >> 16) & 1u)) >> 16;
    return (short)r;
}
__device__ __forceinline__ float bf2f(short b) {
    return __uint_as_float(((unsigned)(unsigned short)b) << 16);
}

// ---- fused histogram: edge degree + batch counts ----
__global__ void k_hist(const int* __restrict__ rows, const int* __restrict__ batch,
                       int* __restrict__ degcnt, int* __restrict__ gcnt, int E, int N) {
    int t = blockIdx.x * blockDim.x + threadIdx.x;
    if (t < E) atomicAdd(&degcnt[rows[t]], 1);
    if (t < N) atomicAdd(&gcnt[batch[t]], 1);
}

// ---- scan step 1 ----
__global__ void k_scan_blocksum(const int* __restrict__ src, int* __restrict__ bsum, int n) {
    __shared__ int s[256];
    int t = threadIdx.x;
    int idx = blockIdx.x * 256 + t;
    int v = idx < n ? src[idx] : 0;
    s[t] = v; __syncthreads();
    for (int off = 128; off > 0; off >>= 1) {
        if (t < off) s[t] += s[t + off];
        __syncthreads();
    }
    if (t == 0) bsum[blockIdx.x] = s[0];
}

// ---- scan step 2 ----
__global__ void k_scan_single(const int* __restrict__ src, int* __restrict__ dst, int n) {
    __shared__ int s[256];
    __shared__ int carry_s;
    int t = threadIdx.x;
    if (t == 0) carry_s = 0;
    __syncthreads();
    for (int base = 0; base < n; base += 256) {
        int idx = base + t;
        int v = idx < n ? src[idx] : 0;
        s[t] = v; __syncthreads();
        for (int off = 1; off < 256; off <<= 1) {
            int x = (t >= off) ? s[t - off] : 0;
            __syncthreads();
            s[t] += x;
            __syncthreads();
        }
        int incl = s[t];
        int carry = carry_s;
        if (idx < n) dst[idx] = carry + incl - v;
        __syncthreads();
        if (t == 255) carry_s = carry + incl;
        __syncthreads();
    }
}

// ---- scan step 3 ----
__global__ void k_scan_final(const int* __restrict__ src, const int* __restrict__ boffs,
                             int* __restrict__ row_ptr, int* __restrict__ cursor,
                             float* __restrict__ dinv, int* __restrict__ gstart,
                             int* __restrict__ bcur, int n, int N, int E) {
    __shared__ int s[256];
    int t = threadIdx.x;
    int idx = blockIdx.x * 256 + t;
    int v = idx < n ? src[idx] : 0;
    s[t] = v; __syncthreads();
    for (int off = 1; off < 256; off <<= 1) {
        int x = (t >= off) ? s[t - off] : 0;
        __syncthreads();
        s[t] += x;
        __syncthreads();
    }
    if (idx < n) {
        int excl = boffs[blockIdx.x] + s[t] - v;
        if (idx < N) {
            row_ptr[idx] = excl;
            cursor[idx] = excl;
            dinv[idx] = rsqrtf((float)v + 1.0f);
            if ((idx & ((1 << BSHIFT) - 1)) == 0) bcur[idx >> BSHIFT] = excl;
        } else {
            if (idx == N) row_ptr[N] = E;
            gstart[idx - N] = excl - E;
        }
    }
}

// ---- scatter phase A: bin edges by row-bucket ----
__global__ __launch_bounds__(256) void k_bin(const int* __restrict__ rows,
                                             const int* __restrict__ cols,
                                             int* __restrict__ bcur,
                                             int2* __restrict__ tmp, int E) {
    __shared__ int lcnt[NBKT];
    __shared__ int lbase[NBKT];
    const int t = threadIdx.x;
    const int e0 = blockIdx.x * BIN_CHUNK;
    for (int i = t; i < NBKT; i += 256) lcnt[i] = 0;
    __syncthreads();
    int r[16];
#pragma unroll
    for (int k = 0; k < 16; ++k) {
        int e = e0 + k * 256 + t;
        r[k] = (e < E) ? rows[e] : -1;
        if (r[k] >= 0) atomicAdd(&lcnt[r[k] >> BSHIFT], 1);
    }
    __syncthreads();
    for (int i = t; i < NBKT; i += 256) lbase[i] = atomicAdd(&bcur[i], lcnt[i]);
    __syncthreads();
    for (int i = t; i < NBKT; i += 256) lcnt[i] = 0;
    __syncthreads();
#pragma unroll
    for (int k = 0; k < 16; ++k) {
        int e = e0 + k * 256 + t;
        if (r[k] >= 0) {
            int b = r[k] >> BSHIFT;
            int p = lbase[b] + atomicAdd(&lcnt[b], 1);
            tmp[p] = make_int2(r[k], cols[e]);
        }
    }
}

// ---- scatter phase B ----
__global__ __launch_bounds__(256) void k_scat2(const int2* __restrict__ tmp,
                                               const int* __restrict__ row_ptr,
                                               int* __restrict__ cursor,
                                               int* __restrict__ colsOut, int N) {
    const int b = blockIdx.x;
    const int s = row_ptr[b << BSHIFT];
    const int endr = min((b + 1) << BSHIFT, N);
    const int tend = row_ptr[endr];
#pragma unroll 4
    for (int e = s + threadIdx.x; e < tend; e += 256) {
        int2 rc = tmp[e];
        int pos = atomicAdd(&cursor[rc.x], 1);
        colsOut[pos] = rc.y;
    }
}

// ---- layer-1 pre-aggregation on raw x (32ch), software-pipelined ----
// Wave owns 64-node chunks; row_ptr/dinv in lane-vectors; next node's cols
// and self row prefetched during current node's gather.
__global__ __launch_bounds__(256, 8) void k_agg32(
        const float* __restrict__ x, const int* __restrict__ row_ptr,
        const int* __restrict__ cols, const float* __restrict__ dinv,
        float* __restrict__ out, int N) {
    const int lane = threadIdx.x & 63;
    const int ch = lane & 31;
    const int hf = lane >> 5;
    int wid = (blockIdx.x * blockDim.x + threadIdx.x) >> 6;
    wid = __builtin_amdgcn_readfirstlane(wid);
    const int nw = (gridDim.x * blockDim.x) >> 6;
    const int nch = N >> 6;   // 6250 exact

    for (int c = wid; c < nch; c += nw) {
        const int i0 = c << 6;
        const int rp  = row_ptr[i0 + lane];
        const int rpn = row_ptr[i0 + lane + 1];
        const float dvv = dinv[i0 + lane];

        int s_cur = rlanei(rp, 0);
        int cnt_cur = rlanei(rpn, 0) - s_cur;
        int colv = (lane < cnt_cur) ? cols[s_cur + lane] : 0;
        float djv = dinv[colv];
        float selfv = x[(size_t)i0 * 32 + ch];

        for (int i = 0; i < 64; ++i) {
            int s_nxt = 0, cnt_nxt = 0, colv_n = 0;
            float djv_n = 0.f, self_n = 0.f;
            if (i < 63) {
                s_nxt = rlanei(rp, i + 1);
                cnt_nxt = rlanei(rpn, i + 1) - s_nxt;
                colv_n = (lane < cnt_nxt) ? cols[s_nxt + lane] : 0;
                self_n = x[(size_t)(i0 + i + 1) * 32 + ch];
                djv_n = dinv[colv_n];
            }
            float acc = 0.0f;
            const int mm = min(cnt_cur, 64);
            const int P = (mm + 1) >> 1;
            int r = 0;
            for (; r + 4 <= P; r += 4) {
#pragma unroll
                for (int k2 = 0; k2 < 4; ++k2) {
                    int e = 2 * (r + k2) + hf;
                    int ei = min(e, 63);
                    int cj = __shfl(colv, ei);
                    float wj = __shfl(djv, ei);
                    if (e >= mm) wj = 0.0f;
                    acc = fmaf(wj, x[(size_t)cj * 32 + ch], acc);
                }
            }
            for (; r < P; ++r) {
                int e = 2 * r + hf;
                int ei = min(e, 63);
                int cj = __shfl(colv, ei);
                float wj = __shfl(djv, ei);
                if (e >= mm) wj = 0.0f;
                acc = fmaf(wj, x[(size_t)cj * 32 + ch], acc);
            }
            // rare: degree > 64
            for (int base = 64; base < cnt_cur; base += 64) {
                int cv = (base + lane < cnt_cur) ? cols[s_cur + base + lane] : 0;
                float dj2 = dinv[cv];
                int m2 = min(cnt_cur - base, 64);
                int P2 = (m2 + 1) >> 1;
                for (int r2 = 0; r2 < P2; ++r2) {
                    int e = 2 * r2 + hf;
                    int ei = min(e, 63);
                    int cj = __shfl(cv, ei);
                    float wj = __shfl(dj2, ei);
                    if (e >= m2) wj = 0.0f;
                    acc = fmaf(wj, x[(size_t)cj * 32 + ch], acc);
                }
            }
            acc += __shfl_xor(acc, 32);
            const float di = rlane(dvv, i);
            float res = di * fmaf(di, selfv, acc);
            if (lane < 32) out[(size_t)(i0 + i) * 32 + ch] = res;
            s_cur = s_nxt; cnt_cur = cnt_nxt; colv = colv_n; djv = djv_n; selfv = self_n;
        }
    }
}

// ---- aggregation (64ch), software-pipelined:
// h[i] = relu( di*(M[i] + sum_j M[j]) + b )
__global__ __launch_bounds__(256, 8) void k_agg(
        const float* __restrict__ M, const float* __restrict__ bias,
        const int* __restrict__ row_ptr, const int* __restrict__ cols,
        const float* __restrict__ dinv, float* __restrict__ out, int N) {
    const int lane = threadIdx.x & 63;
    int wid = (blockIdx.x * blockDim.x + threadIdx.x) >> 6;
    wid = __builtin_amdgcn_readfirstlane(wid);
    const int nw = (gridDim.x * blockDim.x) >> 6;
    const int nch = N >> 6;
    const float b = bias[lane];

    for (int c = wid; c < nch; c += nw) {
        const int i0 = c << 6;
        const int rp  = row_ptr[i0 + lane];
        const int rpn = row_ptr[i0 + lane + 1];
        const float dvv = dinv[i0 + lane];

        int s_cur = rlanei(rp, 0);
        int cnt_cur = rlanei(rpn, 0) - s_cur;
        int colv = (lane < cnt_cur) ? cols[s_cur + lane] : 0;
        float selfv = M[(size_t)i0 * 64 + lane];

        for (int i = 0; i < 64; ++i) {
            int s_nxt = 0, cnt_nxt = 0, colv_n = 0;
            float self_n = 0.f;
            if (i < 63) {
                s_nxt = rlanei(rp, i + 1);
                cnt_nxt = rlanei(rpn, i + 1) - s_nxt;
                colv_n = (lane < cnt_nxt) ? cols[s_nxt + lane] : 0;
                self_n = M[(size_t)(i0 + i + 1) * 64 + lane];
            }
            float acc = selfv;
            const int mm = min(cnt_cur, 64);
            int e = 0;
            for (; e + 8 <= mm; e += 8) {
                int c0 = rlanei(colv, e + 0), c1 = rlanei(colv, e + 1);
                int c2 = rlanei(colv, e + 2), c3 = rlanei(colv, e + 3);
                int c4 = rlanei(colv, e + 4), c5 = rlanei(colv, e + 5);
                int c6 = rlanei(colv, e + 6), c7 = rlanei(colv, e + 7);
                float v0 = M[(size_t)c0 * 64 + lane];
                float v1 = M[(size_t)c1 * 64 + lane];
                float v2 = M[(size_t)c2 * 64 + lane];
                float v3 = M[(size_t)c3 * 64 + lane];
                float v4 = M[(size_t)c4 * 64 + lane];
                float v5 = M[(size_t)c5 * 64 + lane];
                float v6 = M[(size_t)c6 * 64 + lane];
                float v7 = M[(size_t)c7 * 64 + lane];
                acc += (((v0 + v1) + (v2 + v3)) + ((v4 + v5) + (v6 + v7)));
            }
            for (; e + 4 <= mm; e += 4) {
                int c0 = rlanei(colv, e + 0), c1 = rlanei(colv, e + 1);
                int c2 = rlanei(colv, e + 2), c3 = rlanei(colv, e + 3);
                float v0 = M[(size_t)c0 * 64 + lane];
                float v1 = M[(size_t)c1 * 64 + lane];
                float v2 = M[(size_t)c2 * 64 + lane];
                float v3 = M[(size_t)c3 * 64 + lane];
                acc += ((v0 + v1) + (v2 + v3));
            }
            for (; e < mm; ++e) acc += M[(size_t)rlanei(colv, e) * 64 + lane];
            for (int base = 64; base < cnt_cur; base += 64) {
                int cv = (base + lane < cnt_cur) ? cols[s_cur + base + lane] : 0;
                int m2 = min(cnt_cur - base, 64);
                for (int e2 = 0; e2 < m2; ++e2)
                    acc += M[(size_t)rlanei(cv, e2) * 64 + lane];
            }
            const float di = rlane(dvv, i);
            out[(size_t)(i0 + i) * 64 + lane] = fmaxf(fmaf(di, acc, b), 0.0f);
            s_cur = s_nxt; cnt_cur = cnt_nxt; colv = colv_n; selfv = self_n;
        }
    }
}

// ---- MFMA GEMM, split-bf16 hi/lo. PRESCALE: scale A rows by dinv.
// BIASRELU: epilogue out = relu(C + bias[col]).
template <int IN_D, bool PRESCALE, bool BIASRELU>
__global__ __launch_bounds__(256, 4) void k_gemm_mfma(
        const float* __restrict__ in, const float* __restrict__ W,
        const float* __restrict__ dinv, const float* __restrict__ bias,
        float* __restrict__ out, int N) {
    constexpr int KT = IN_D / 32;
    const int lane = threadIdx.x & 63;
    const int wave = threadIdx.x >> 6;
    const int m = lane & 15;
    const int q = lane >> 4;

    bf16x8 Bhi[4][KT], Blo[4][KT];
#pragma unroll
    for (int nt = 0; nt < 4; ++nt) {
#pragma unroll
        for (int kt = 0; kt < KT; ++kt) {
#pragma unroll
            for (int j = 0; j < 8; ++j) {
                int k = kt * 32 + q * 8 + j;
                float w = W[k * 64 + nt * 16 + m];
                short hi = f2bf(w);
                Bhi[nt][kt][j] = hi;
                Blo[nt][kt][j] = f2bf(w - bf2f(hi));
            }
        }
    }

    const int tile = blockIdx.x * 4 + wave;
    const int node0 = tile * 16;
    if (node0 >= N) return;

    const float dv = PRESCALE ? dinv[node0 + m] : 1.0f;
    const float* rowp = in + (size_t)(node0 + m) * IN_D + q * 8;

    bf16x8 Ahi[KT], Alo[KT];
#pragma unroll
    for (int kt = 0; kt < KT; ++kt) {
        f32x4 a0 = *(const f32x4*)(rowp + kt * 32);
        f32x4 a1 = *(const f32x4*)(rowp + kt * 32 + 4);
#pragma unroll
        for (int j = 0; j < 4; ++j) {
            float xx = PRESCALE ? dv * a0[j] : a0[j];
            short hi = f2bf(xx);
            Ahi[kt][j] = hi;
            Alo[kt][j] = f2bf(xx - bf2f(hi));
        }
#pragma unroll
        for (int j = 0; j < 4; ++j) {
            float xx = PRESCALE ? dv * a1[j] : a1[j];
            short hi = f2bf(xx);
            Ahi[kt][4 + j] = hi;
            Alo[kt][4 + j] = f2bf(xx - bf2f(hi));
        }
    }

    f32x4 C[4];
#pragma unroll
    for (int nt = 0; nt < 4; ++nt) C[nt] = (f32x4){0.f, 0.f, 0.f, 0.f};

#pragma unroll
    for (int nt = 0; nt < 4; ++nt) {
#pragma unroll
        for (int kt = 0; kt < KT; ++kt) {
            C[nt] = __builtin_amdgcn_mfma_f32_16x16x32_bf16(Ahi[kt], Bhi[nt][kt], C[nt], 0, 0, 0);
            C[nt] = __builtin_amdgcn_mfma_f32_16x16x32_bf16(Ahi[kt], Blo[nt][kt], C[nt], 0, 0, 0);
            C[nt] = __builtin_amdgcn_mfma_f32_16x16x32_bf16(Alo[kt], Bhi[nt][kt], C[nt], 0, 0, 0);
        }
    }

    float br[4];
    if (BIASRELU) {
#pragma unroll
        for (int nt = 0; nt < 4; ++nt) br[nt] = bias[nt * 16 + m];
    }

    float* op = out + (size_t)node0 * 64;
#pragma unroll
    for (int nt = 0; nt < 4; ++nt) {
#pragma unroll
        for (int r = 0; r < 4; ++r) {
            int row = q * 4 + r;
            float v = C[nt][r];
            if (BIASRELU) v = fmaxf(v + br[nt], 0.0f);
            op[(size_t)row * 64 + nt * 16 + m] = v;
        }
    }
}

// ---- fused layer-3 agg + mean/max pool + meta encoder, pipelined ----
__global__ __launch_bounds__(256, 8) void k_agg_pool(
        const float* __restrict__ M, const float* __restrict__ b3,
        const int* __restrict__ row_ptr, const int* __restrict__ cols,
        const float* __restrict__ dinv,
        const int* __restrict__ gstart, const int* __restrict__ gcnt,
        const float* __restrict__ metadata, const int* __restrict__ species,
        const float* __restrict__ emb, const float* __restrict__ Wm,
        const float* __restrict__ bm, float* __restrict__ fused, int G) {
    const int lane = threadIdx.x & 63;
    int wv = (blockIdx.x * blockDim.x + threadIdx.x) >> 6;
    wv = __builtin_amdgcn_readfirstlane(wv);
    const int nw = (gridDim.x * blockDim.x) >> 6;
    const float b = b3[lane];
    const float bmr = bm[lane];
    float wmr[16];
#pragma unroll
    for (int k = 0; k < 16; ++k) wmr[k] = Wm[k * 64 + lane];

    for (int g = wv; g < G; g += nw) {
        const int gs = gstart[g];
        const int gc = gcnt[g];
        float sum = 0.0f;
        float mx = -3.402823466e38f;
        if (gc > 0 && gc <= 63) {
            // fast path: whole graph's row_ptr/dinv in lane-vectors, pipelined
            const int rp = row_ptr[gs + min(lane, gc)];
            const float dvv = dinv[gs + min(lane, gc - 1)];
            int s_cur = rlanei(rp, 0);
            int cnt_cur = rlanei(rp, 1) - s_cur;
            int colv = (lane < cnt_cur) ? cols[s_cur + lane] : 0;
            float selfv = M[(size_t)gs * 64 + lane];
            for (int r = 0; r < gc; ++r) {
                int s_nxt = 0, cnt_nxt = 0, colv_n = 0;
                float self_n = 0.f;
                if (r + 1 < gc) {
                    s_nxt = rlanei(rp, r + 1);
                    cnt_nxt = rlanei(rp, r + 2) - s_nxt;
                    colv_n = (lane < cnt_nxt) ? cols[s_nxt + lane] : 0;
                    self_n = M[(size_t)(gs + r + 1) * 64 + lane];
                }
                float acc = selfv;
                const int mm = min(cnt_cur, 64);
                int e = 0;
                for (; e + 8 <= mm; e += 8) {
                    int c0 = rlanei(colv, e + 0), c1 = rlanei(colv, e + 1);
                    int c2 = rlanei(colv, e + 2), c3 = rlanei(colv, e + 3);
                    int c4 = rlanei(colv, e + 4), c5 = rlanei(colv, e + 5);
                    int c6 = rlanei(colv, e + 6), c7 = rlanei(colv, e + 7);
                    float v0 = M[(size_t)c0 * 64 + lane];
                    float v1 = M[(size_t)c1 * 64 + lane];
                    float v2 = M[(size_t)c2 * 64 + lane];
                    float v3 = M[(size_t)c3 * 64 + lane];
                    float v4 = M[(size_t)c4 * 64 + lane];
                    float v5 = M[(size_t)c5 * 64 + lane];
                    float v6 = M[(size_t)c6 * 64 + lane];
                    float v7 = M[(size_t)c7 * 64 + lane];
                    acc += (((v0 + v1) + (v2 + v3)) + ((v4 + v5) + (v6 + v7)));
                }
                for (; e + 4 <= mm; e += 4) {
                    int c0 = rlanei(colv, e + 0), c1 = rlanei(colv, e + 1);
                    int c2 = rlanei(colv, e + 2), c3 = rlanei(colv, e + 3);
                    float v0 = M[(size_t)c0 * 64 + lane];
                    float v1 = M[(size_t)c1 * 64 + lane];
                    float v2 = M[(size_t)c2 * 64 + lane];
                    float v3 = M[(size_t)c3 * 64 + lane];
                    acc += ((v0 + v1) + (v2 + v3));
                }
                for (; e < mm; ++e) acc += M[(size_t)rlanei(colv, e) * 64 + lane];
                for (int base = 64; base < cnt_cur; base += 64) {
                    int cv = (base + lane < cnt_cur) ? cols[s_cur + base + lane] : 0;
                    int m2 = min(cnt_cur - base, 64);
                    for (int e2 = 0; e2 < m2; ++e2)
                        acc += M[(size_t)rlanei(cv, e2) * 64 + lane];
                }
                const float di = rlane(dvv, r);
                float h = fmaxf(fmaf(di, acc, b), 0.0f);
                sum += h;
                mx = fmaxf(mx, h);
                s_cur = s_nxt; cnt_cur = cnt_nxt; colv = colv_n; selfv = self_n;
            }
        } else if (gc > 0) {
            // slow path (gc > 63)
            for (int i = gs; i < gs + gc; ++i) {
                const int s0 = row_ptr[i];
                const int s1 = row_ptr[i + 1];
                const float di = dinv[i];
                float acc = M[(size_t)i * 64 + lane];
                int e = s0;
                for (; e + 4 <= s1; e += 4) {
                    int c0 = cols[e + 0], c1 = cols[e + 1];
                    int c2 = cols[e + 2], c3 = cols[e + 3];
                    float v0 = M[(size_t)c0 * 64 + lane];
                    float v1 = M[(size_t)c1 * 64 + lane];
                    float v2 = M[(size_t)c2 * 64 + lane];
                    float v3 = M[(size_t)c3 * 64 + lane];
                    acc += ((v0 + v1) + (v2 + v3));
                }
                for (; e < s1; ++e) acc += M[(size_t)cols[e] * 64 + lane];
                float h = fmaxf(fmaf(di, acc, b), 0.0f);
                sum += h;
                mx = fmaxf(mx, h);
            }
        }
        float mean = sum / fmaxf((float)gc, 1.0f);
        if (gc == 0) mx = 0.0f;
        float md = lane < 16 ? metadata[(size_t)g * 16 + lane] : 0.0f;
        float mval = bmr;
#pragma unroll
        for (int k = 0; k < 16; ++k) mval = fmaf(rlane(md, k), wmr[k], mval);
        mval = fmaxf(mval, 0.0f);
        const int sid = species[g];
        float* fr = fused + (size_t)g * 224;
        fr[lane] = mean;
        fr[64 + lane] = mx;
        fr[128 + lane] = mval;
        if (lane < 16) fr[192 + lane] = emb[(size_t)sid * 16 + lane];
        else if (lane < 32) fr[192 + lane] = 0.0f;
    }
}

// ---- MFMA predictor head: out = relu(fused @ Wp1 + bp1) @ Wp2 + bp2 ----
__global__ __launch_bounds__(256, 2) void k_pred_mfma(
        const float* __restrict__ fused, const float* __restrict__ Wp1,
        const float* __restrict__ bp1, const float* __restrict__ Wp2,
        const float* __restrict__ bp2, float* __restrict__ out, int G) {
    __shared__ __align__(16) short Whi[64 * 232];
    __shared__ __align__(16) short Wlo[64 * 232];
    const int t = threadIdx.x;
    for (int idx = t; idx < 64 * 232; idx += 256) {
        int n = idx / 232;
        int k = idx % 232;
        float w = (k < 208) ? Wp1[(size_t)k * 64 + n] : 0.0f;
        short hi = f2bf(w);
        Whi[n * 232 + k] = hi;
        Wlo[n * 232 + k] = f2bf(w - bf2f(hi));
    }
    __syncthreads();

    const int lane = t & 63;
    const int wave = t >> 6;
    const int m = lane & 15;
    const int q = lane >> 4;
    const int g0 = (blockIdx.x * 4 + wave) * 16;
    if (g0 >= G) return;

    const float* rowp = fused + (size_t)(g0 + m) * 224 + q * 8;

    f32x4 C[4];
#pragma unroll
    for (int nt = 0; nt < 4; ++nt) C[nt] = (f32x4){0.f, 0.f, 0.f, 0.f};

#pragma unroll
    for (int kt = 0; kt < 7; ++kt) {
        f32x4 a0 = *(const f32x4*)(rowp + kt * 32);
        f32x4 a1 = *(const f32x4*)(rowp + kt * 32 + 4);
        bf16x8 Ahi, Alo;
#pragma unroll
        for (int j = 0; j < 4; ++j) {
            short hi = f2bf(a0[j]);
            Ahi[j] = hi;
            Alo[j] = f2bf(a0[j] - bf2f(hi));
        }
#pragma unroll
        for (int j = 0; j < 4; ++j) {
            short hi = f2bf(a1[j]);
            Ahi[4 + j] = hi;
            Alo[4 + j] = f2bf(a1[j] - bf2f(hi));
        }
#pragma unroll
        for (int nt = 0; nt < 4; ++nt) {
            const int boff = (nt * 16 + m) * 232 + kt * 32 + q * 8;
            bf16x8 Bh = *(const bf16x8*)&Whi[boff];
            bf16x8 Bl = *(const bf16x8*)&Wlo[boff];
            C[nt] = __builtin_amdgcn_mfma_f32_16x16x32_bf16(Ahi, Bh, C[nt], 0, 0, 0);
            C[nt] = __builtin_amdgcn_mfma_f32_16x16x32_bf16(Ahi, Bl, C[nt], 0, 0, 0);
            C[nt] = __builtin_amdgcn_mfma_f32_16x16x32_bf16(Alo, Bh, C[nt], 0, 0, 0);
        }
    }

    float wp2r[4], bp1r[4];
#pragma unroll
    for (int nt = 0; nt < 4; ++nt) {
        wp2r[nt] = Wp2[nt * 16 + m];
        bp1r[nt] = bp1[nt * 16 + m];
    }
    const float bp2v = bp2[0];
    float s[4];
#pragma unroll
    for (int r = 0; r < 4; ++r) {
        float acc = 0.0f;
#pragma unroll
        for (int nt = 0; nt < 4; ++nt)
            acc += fmaxf(C[nt][r] + bp1r[nt], 0.0f) * wp2r[nt];
        s[r] = acc;
    }
#pragma unroll
    for (int off = 1; off < 16; off <<= 1) {
#pragma unroll
        for (int r = 0; r < 4; ++r) s[r] += __shfl_xor(s[r], off);
    }
    if (m == 0) {
#pragma unroll
        for (int r = 0; r < 4; ++r) out[g0 + q * 4 + r] = s[r] + bp2v;
    }
}

extern "C" void kernel_launch(void* const* d_in, const int* in_sizes, int n_in,
                              void* d_out, int out_size, void* d_ws, size_t ws_size,
                              hipStream_t stream) {
    const int N = N_NODES, E = N_EDGES, G = N_GRAPHS;
    const int NT = N + G;

    const float* x        = (const float*)d_in[0];
    const float* metadata = (const float*)d_in[1];
    const int*   ei       = (const int*)d_in[2];
    const int*   batch    = (const int*)d_in[3];
    const int*   species  = (const int*)d_in[4];
    const float* W1 = (const float*)d_in[5];
    const float* b1 = (const float*)d_in[6];
    const float* W2 = (const float*)d_in[7];
    const float* b2 = (const float*)d_in[8];
    const float* W3 = (const float*)d_in[9];
    const float* b3 = (const float*)d_in[10];
    const float* Wm = (const float*)d_in[11];
    const float* bm = (const float*)d_in[12];
    const float* emb = (const float*)d_in[13];
    const float* Wp1 = (const float*)d_in[14];
    const float* bp1 = (const float*)d_in[15];
    const float* Wp2 = (const float*)d_in[16];
    const float* bp2 = (const float*)d_in[17];
    float* out = (float*)d_out;

    char* ws = (char*)d_ws;
    size_t off = 0;
    auto alloc = [&](size_t bytes) -> void* {
        void* p = ws + off;
        off = (off + bytes + 255) & ~(size_t)255;
        return p;
    };
    int*   cnt     = (int*)alloc((size_t)NT * 4);
    int*   row_ptr = (int*)alloc((size_t)(N + 1) * 4);
    int*   cursor  = (int*)alloc((size_t)N * 4);
    float* dinv    = (float*)alloc((size_t)N * 4);
    int*   gstart  = (int*)alloc((size_t)G * 4);
    int*   bsum    = (int*)alloc(2048 * 4);
    int*   boffs   = (int*)alloc(2048 * 4);
    int*   bcur    = (int*)alloc((size_t)NBKT * 4);
    int*   colsS   = (int*)alloc((size_t)E * 4);
    float* hA      = (float*)alloc((size_t)N * 64 * 4);
    float* hB      = (float*)alloc((size_t)N * 64 * 4);
    float* fused   = (float*)alloc((size_t)G * 224 * 4);

    int* degcnt = cnt;
    int* gcnt = cnt + N;
    int2* tmp = (int2*)hA;        // aliases hA: dead until layer-1 GEMM writes it

    const int nbE = (E + 255) / 256;    // 6250
    const int nbT = (NT + 255) / 256;   // 1627
    const int nbG = (N / 16 + 3) / 4;   // 6250 blocks, 4 tiles each

    hipMemsetAsync(cnt, 0, (size_t)NT * 4, stream);

    k_hist<<<nbE, 256, 0, stream>>>(ei, batch, degcnt, gcnt, E, N);
    k_scan_blocksum<<<nbT, 256, 0, stream>>>(cnt, bsum, NT);
    k_scan_single<<<1, 256, 0, stream>>>(bsum, boffs, nbT);
    k_scan_final<<<nbT, 256, 0, stream>>>(cnt, boffs, row_ptr, cursor, dinv, gstart,
                                          bcur, NT, N, E);
    k_bin<<<(E + BIN_CHUNK - 1) / BIN_CHUNK, 256, 0, stream>>>(ei, ei + E, bcur, tmp, E);
    k_scat2<<<NBKT, 256, 0, stream>>>(tmp, row_ptr, cursor, colsS, N);

    // layer 1 (reordered): xa = Dinv(A+I)Dinv x, then h1 = relu(xa@W1 + b1)
    k_agg32<<<1563, 256, 0, stream>>>(x, row_ptr, colsS, dinv, hB, N);
    k_gemm_mfma<32, false, true><<<nbG, 256, 0, stream>>>(hB, W1, dinv, b1, hA, N);
    // layer 2
    k_gemm_mfma<64, true, false><<<nbG, 256, 0, stream>>>(hA, W2, dinv, b2, hB, N);
    k_agg<<<1563, 256, 0, stream>>>(hB, b2, row_ptr, colsS, dinv, hA, N);
    // layer 3 GEMM, then fused agg+pool+meta+assembly
    k_gemm_mfma<64, true, false><<<nbG, 256, 0, stream>>>(hA, W3, dinv, b3, hB, N);
    k_agg_pool<<<2048, 256, 0, stream>>>(hB, b3, row_ptr, colsS, dinv, gstart, gcnt,
                                         metadata, species, emb, Wm, bm, fused, G);

    // predictor head (MFMA)
    k_pred_mfma<<<(G / 16 + 3) / 4, 256, 0, stream>>>(fused, Wp1, bp1, Wp2, bp2, out, G);
}

// Round 9
// 702.631 us; speedup vs baseline: 1.3873x; 1.0306x over previous
//
#include <hip/hip_runtime.h>
#include <hip/hip_bf16.h>

#define N_NODES 400000
#define N_EDGES 1600000
#define N_GRAPHS 16384
#define CHUNK 32
#define NCHUNK (N_NODES / CHUNK)   // 12500

#define BSHIFT 11
#define NBKT ((N_NODES + (1 << BSHIFT) - 1) >> BSHIFT)   // 196 row-buckets
#define BIN_CHUNK 4096

typedef __attribute__((ext_vector_type(8))) short bf16x8;
typedef __attribute__((ext_vector_type(4))) float f32x4;

__device__ __forceinline__ float rlane(float x, int k) {
    return __int_as_float(__builtin_amdgcn_readlane(__float_as_int(x), k));
}
__device__ __forceinline__ int rlanei(int x, int k) {
    return __builtin_amdgcn_readlane(x, k);
}

__device__ __forceinline__ short f2bf(float x) {  // RNE float -> bf16 bits
    unsigned u = __float_as_uint(x);
    unsigned r = (u + 0x7fffu + ((u >> 16) & 1u)) >> 16;
    return (short)r;
}
__device__ __forceinline__ float bf2f(short b) {
    return __uint_as_float(((unsigned)(unsigned short)b) << 16);
}

// ---- fused histogram ----
__global__ void k_hist(const int* __restrict__ rows, const int* __restrict__ batch,
                       int* __restrict__ degcnt, int* __restrict__ gcnt, int E, int N) {
    int t = blockIdx.x * blockDim.x + threadIdx.x;
    if (t < E) atomicAdd(&degcnt[rows[t]], 1);
    if (t < N) atomicAdd(&gcnt[batch[t]], 1);
}

__global__ void k_scan_blocksum(const int* __restrict__ src, int* __restrict__ bsum, int n) {
    __shared__ int s[256];
    int t = threadIdx.x;
    int idx = blockIdx.x * 256 + t;
    int v = idx < n ? src[idx] : 0;
    s[t] = v; __syncthreads();
    for (int off = 128; off > 0; off >>= 1) {
        if (t < off) s[t] += s[t + off];
        __syncthreads();
    }
    if (t == 0) bsum[blockIdx.x] = s[0];
}

__global__ void k_scan_single(const int* __restrict__ src, int* __restrict__ dst, int n) {
    __shared__ int s[256];
    __shared__ int carry_s;
    int t = threadIdx.x;
    if (t == 0) carry_s = 0;
    __syncthreads();
    for (int base = 0; base < n; base += 256) {
        int idx = base + t;
        int v = idx < n ? src[idx] : 0;
        s[t] = v; __syncthreads();
        for (int off = 1; off < 256; off <<= 1) {
            int x = (t >= off) ? s[t - off] : 0;
            __syncthreads();
            s[t] += x;
            __syncthreads();
        }
        int incl = s[t];
        int carry = carry_s;
        if (idx < n) dst[idx] = carry + incl - v;
        __syncthreads();
        if (t == 255) carry_s = carry + incl;
        __syncthreads();
    }
}

__global__ void k_scan_final(const int* __restrict__ src, const int* __restrict__ boffs,
                             int* __restrict__ row_ptr, int* __restrict__ cursor,
                             float* __restrict__ dinv, int* __restrict__ gstart,
                             int* __restrict__ bcur, int n, int N, int E) {
    __shared__ int s[256];
    int t = threadIdx.x;
    int idx = blockIdx.x * 256 + t;
    int v = idx < n ? src[idx] : 0;
    s[t] = v; __syncthreads();
    for (int off = 1; off < 256; off <<= 1) {
        int x = (t >= off) ? s[t - off] : 0;
        __syncthreads();
        s[t] += x;
        __syncthreads();
    }
    if (idx < n) {
        int excl = boffs[blockIdx.x] + s[t] - v;
        if (idx < N) {
            row_ptr[idx] = excl;
            cursor[idx] = excl;
            dinv[idx] = rsqrtf((float)v + 1.0f);
            if ((idx & ((1 << BSHIFT) - 1)) == 0) bcur[idx >> BSHIFT] = excl;
        } else {
            if (idx == N) row_ptr[N] = E;
            gstart[idx - N] = excl - E;
        }
    }
}

// ---- scatter phase A ----
__global__ __launch_bounds__(256) void k_bin(const int* __restrict__ rows,
                                             const int* __restrict__ cols,
                                             int* __restrict__ bcur,
                                             int2* __restrict__ tmp, int E) {
    __shared__ int lcnt[NBKT];
    __shared__ int lbase[NBKT];
    const int t = threadIdx.x;
    const int e0 = blockIdx.x * BIN_CHUNK;
    for (int i = t; i < NBKT; i += 256) lcnt[i] = 0;
    __syncthreads();
    int r[16];
#pragma unroll
    for (int k = 0; k < 16; ++k) {
        int e = e0 + k * 256 + t;
        r[k] = (e < E) ? rows[e] : -1;
        if (r[k] >= 0) atomicAdd(&lcnt[r[k] >> BSHIFT], 1);
    }
    __syncthreads();
    for (int i = t; i < NBKT; i += 256) lbase[i] = atomicAdd(&bcur[i], lcnt[i]);
    __syncthreads();
    for (int i = t; i < NBKT; i += 256) lcnt[i] = 0;
    __syncthreads();
#pragma unroll
    for (int k = 0; k < 16; ++k) {
        int e = e0 + k * 256 + t;
        if (r[k] >= 0) {
            int b = r[k] >> BSHIFT;
            int p = lbase[b] + atomicAdd(&lcnt[b], 1);
            tmp[p] = make_int2(r[k], cols[e]);
        }
    }
}

// ---- scatter phase B ----
__global__ __launch_bounds__(256) void k_scat2(const int2* __restrict__ tmp,
                                               const int* __restrict__ row_ptr,
                                               int* __restrict__ cursor,
                                               int* __restrict__ colsOut, int N) {
    const int b = blockIdx.x;
    const int s = row_ptr[b << BSHIFT];
    const int endr = min((b + 1) << BSHIFT, N);
    const int tend = row_ptr[endr];
#pragma unroll 4
    for (int e = s + threadIdx.x; e < tend; e += 256) {
        int2 rc = tmp[e];
        int pos = atomicAdd(&cursor[rc.x], 1);
        colsOut[pos] = rc.y;
    }
}

// ---- MFMA GEMM (grid-stride over 16-node tiles), split-bf16 hi/lo ----
template <int IN_D, bool PRESCALE>
__global__ __launch_bounds__(256, 4) void k_gemm_mfma(
        const float* __restrict__ in, const float* __restrict__ W,
        const float* __restrict__ dinv, float* __restrict__ out, int nTiles) {
    constexpr int KT = IN_D / 32;
    const int lane = threadIdx.x & 63;
    const int m = lane & 15;
    const int q = lane >> 4;

    bf16x8 Bhi[4][KT], Blo[4][KT];
#pragma unroll
    for (int nt = 0; nt < 4; ++nt) {
#pragma unroll
        for (int kt = 0; kt < KT; ++kt) {
#pragma unroll
            for (int j = 0; j < 8; ++j) {
                int k = kt * 32 + q * 8 + j;
                float w = W[k * 64 + nt * 16 + m];
                short hi = f2bf(w);
                Bhi[nt][kt][j] = hi;
                Blo[nt][kt][j] = f2bf(w - bf2f(hi));
            }
        }
    }

    const int wv = (blockIdx.x * 256 + threadIdx.x) >> 6;
    const int nwv = (gridDim.x * 256) >> 6;

    for (int tile = wv; tile < nTiles; tile += nwv) {
        const int node0 = tile * 16;
        const float dv = PRESCALE ? dinv[node0 + m] : 1.0f;
        const float* rowp = in + (size_t)(node0 + m) * IN_D + q * 8;

        bf16x8 Ahi[KT], Alo[KT];
#pragma unroll
        for (int kt = 0; kt < KT; ++kt) {
            f32x4 a0 = *(const f32x4*)(rowp + kt * 32);
            f32x4 a1 = *(const f32x4*)(rowp + kt * 32 + 4);
#pragma unroll
            for (int j = 0; j < 4; ++j) {
                float xx = PRESCALE ? dv * a0[j] : a0[j];
                short hi = f2bf(xx);
                Ahi[kt][j] = hi;
                Alo[kt][j] = f2bf(xx - bf2f(hi));
            }
#pragma unroll
            for (int j = 0; j < 4; ++j) {
                float xx = PRESCALE ? dv * a1[j] : a1[j];
                short hi = f2bf(xx);
                Ahi[kt][4 + j] = hi;
                Alo[kt][4 + j] = f2bf(xx - bf2f(hi));
            }
        }

        f32x4 C[4];
#pragma unroll
        for (int nt = 0; nt < 4; ++nt) C[nt] = (f32x4){0.f, 0.f, 0.f, 0.f};
#pragma unroll
        for (int nt = 0; nt < 4; ++nt) {
#pragma unroll
            for (int kt = 0; kt < KT; ++kt) {
                C[nt] = __builtin_amdgcn_mfma_f32_16x16x32_bf16(Ahi[kt], Bhi[nt][kt], C[nt], 0, 0, 0);
                C[nt] = __builtin_amdgcn_mfma_f32_16x16x32_bf16(Ahi[kt], Blo[nt][kt], C[nt], 0, 0, 0);
                C[nt] = __builtin_amdgcn_mfma_f32_16x16x32_bf16(Alo[kt], Bhi[nt][kt], C[nt], 0, 0, 0);
            }
        }

        float* op = out + (size_t)node0 * 64;
#pragma unroll
        for (int nt = 0; nt < 4; ++nt) {
#pragma unroll
            for (int r = 0; r < 4; ++r) {
                op[(size_t)(q * 4 + r) * 64 + nt * 16 + m] = C[nt][r];
            }
        }
    }
}

// ==== segmented-stream aggregation ====
// Wave owns a CHUNK(32)-node range; its CSR edges [S,T) form a flat stream.
// cols read via lane-vector batches; an 8-deep ring of row-gathers stays in
// flight across node boundaries; scalar bookkeeping finalizes nodes.
// POOL=0: out[i] = dinv[i] * relu(dinv[i]*(M_i + sum_j M_j) + b)   (pre-scaled)
// POOL=1: h3 = relu(...) pooled per graph-run -> atomics into psum/pmax.
template <int POOL>
__global__ __launch_bounds__(256, 8) void k_agg_seg(
        const float* __restrict__ M, const float* __restrict__ bias,
        const int* __restrict__ row_ptr, const int* __restrict__ cols,
        const float* __restrict__ dinv, const int* __restrict__ batch,
        float* __restrict__ out, float* __restrict__ psum,
        float* __restrict__ pmax) {
    const int lane = threadIdx.x & 63;
    int wid = (blockIdx.x * blockDim.x + threadIdx.x) >> 6;
    wid = __builtin_amdgcn_readfirstlane(wid);
    const int nw = (gridDim.x * blockDim.x) >> 6;
    const float b = bias[lane];

    for (int c = wid; c < NCHUNK; c += nw) {
        const int i0 = c * CHUNK;
        const int rpn = row_ptr[i0 + min(lane, CHUNK - 1) + 1];  // bnd per node
        const int S = row_ptr[i0];
        const int ne = rlanei(rpn, CHUNK - 1) - S;
        const float dvv = dinv[i0 + min(lane, CHUNK - 1)];
        const int bvv = POOL ? batch[i0 + min(lane, CHUNK - 1)] : 0;

        int node = 0;
        int bnd = rlanei(rpn, 0) - S;
        float acc = 0.0f;
        float selfA = M[(size_t)i0 * 64 + lane];
        float selfB = M[(size_t)(i0 + 1) * 64 + lane];
        float selfC = M[(size_t)(i0 + 2) * 64 + lane];
        int gcur = POOL ? rlanei(bvv, 0) : 0;
        float rsum = 0.0f, rmax = 0.0f;

        auto flush = [&]() {
            if (POOL) {
                atomicAdd(&psum[(size_t)gcur * 64 + lane], rsum);
                atomicMax((int*)&pmax[(size_t)gcur * 64 + lane], __float_as_int(rmax));
            }
        };
        auto finalize = [&]() {
            const float d = rlane(dvv, node);
            const float h = fmaxf(fmaf(d, selfA + acc, b), 0.0f);
            if (POOL) {
                const int g = rlanei(bvv, node);
                if (g != gcur) { flush(); gcur = g; rsum = 0.0f; rmax = 0.0f; }
                rsum += h;
                rmax = fmaxf(rmax, h);
            } else {
                out[(size_t)(i0 + node) * 64 + lane] = d * h;
            }
            acc = 0.0f;
            selfA = selfB;
            selfB = selfC;
            if (node + 3 < CHUNK) selfC = M[(size_t)(i0 + node + 3) * 64 + lane];
            ++node;
            if (node < CHUNK) bnd = rlanei(rpn, node) - S;
        };

        if (ne > 0) {
            int bidx = 0;
            int a0 = S + lane, a1 = S + 64 + lane;
            int colv0 = (a0 < S + ne) ? cols[a0] : 0;
            int colv1 = (a1 < S + ne) ? cols[a1] : 0;
            float vbuf[8];
#pragma unroll
            for (int k = 0; k < 8; ++k) {
                int e = min(k, ne - 1);
                int cc = rlanei(colv0, e);
                vbuf[k] = M[(size_t)cc * 64 + lane];
            }

            int j = 0;
            while (j + 8 <= ne) {
#pragma unroll
                for (int k = 0; k < 8; ++k) {
                    const int jj = j + k;
                    if ((jj & 63) == 0 && jj != 0) {
                        colv0 = colv1;
                        ++bidx;
                        int ad = S + (bidx + 1) * 64 + lane;
                        colv1 = (ad < S + ne) ? cols[ad] : 0;
                    }
                    while (jj == bnd) finalize();
                    acc += vbuf[k];
                    int ec = min(jj + 8, ne - 1);
                    int src = ((ec >> 6) == bidx) ? colv0 : colv1;
                    int cc = rlanei(src, ec & 63);
                    vbuf[k] = M[(size_t)cc * 64 + lane];
                }
                j += 8;
            }
            for (; j < ne; ++j) {
                while (j == bnd) finalize();
                acc += vbuf[j & 7];
            }
        }
        while (node < CHUNK) finalize();
        flush();
    }
}

// ---- assemble fused vector: [mean | max | relu(meta@Wm+bm) | emb | pad] ----
__global__ __launch_bounds__(256) void k_asm(
        const float* __restrict__ psum, const float* __restrict__ pmax,
        const int* __restrict__ gcnt, const float* __restrict__ metadata,
        const int* __restrict__ species, const float* __restrict__ emb,
        const float* __restrict__ Wm, const float* __restrict__ bm,
        float* __restrict__ fused, int G) {
    const int lane = threadIdx.x & 63;
    int wv = (blockIdx.x * blockDim.x + threadIdx.x) >> 6;
    const int nw = (gridDim.x * blockDim.x) >> 6;
    const float bmr = bm[lane];
    float wmr[16];
#pragma unroll
    for (int k = 0; k < 16; ++k) wmr[k] = Wm[k * 64 + lane];
    for (int g = wv; g < G; g += nw) {
        float gc = (float)gcnt[g];
        float mean = psum[(size_t)g * 64 + lane] / fmaxf(gc, 1.0f);
        float mx = pmax[(size_t)g * 64 + lane];
        float md = lane < 16 ? metadata[(size_t)g * 16 + lane] : 0.0f;
        float mval = bmr;
#pragma unroll
        for (int k = 0; k < 16; ++k) mval = fmaf(rlane(md, k), wmr[k], mval);
        mval = fmaxf(mval, 0.0f);
        const int sid = species[g];
        float* fr = fused + (size_t)g * 224;
        fr[lane] = mean;
        fr[64 + lane] = mx;
        fr[128 + lane] = mval;
        if (lane < 16) fr[192 + lane] = emb[(size_t)sid * 16 + lane];
        else if (lane < 32) fr[192 + lane] = 0.0f;
    }
}

// ---- MFMA predictor head ----
__global__ __launch_bounds__(256, 2) void k_pred_mfma(
        const float* __restrict__ fused, const float* __restrict__ Wp1,
        const float* __restrict__ bp1, const float* __restrict__ Wp2,
        const float* __restrict__ bp2, float* __restrict__ out, int G) {
    __shared__ __align__(16) short Whi[64 * 232];
    __shared__ __align__(16) short Wlo[64 * 232];
    const int t = threadIdx.x;
    for (int idx = t; idx < 64 * 232; idx += 256) {
        int n = idx / 232;
        int k = idx % 232;
        float w = (k < 208) ? Wp1[(size_t)k * 64 + n] : 0.0f;
        short hi = f2bf(w);
        Whi[n * 232 + k] = hi;
        Wlo[n * 232 + k] = f2bf(w - bf2f(hi));
    }
    __syncthreads();

    const int lane = t & 63;
    const int wave = t >> 6;
    const int m = lane & 15;
    const int q = lane >> 4;
    const int g0 = (blockIdx.x * 4 + wave) * 16;
    if (g0 >= G) return;

    const float* rowp = fused + (size_t)(g0 + m) * 224 + q * 8;

    f32x4 C[4];
#pragma unroll
    for (int nt = 0; nt < 4; ++nt) C[nt] = (f32x4){0.f, 0.f, 0.f, 0.f};

#pragma unroll
    for (int kt = 0; kt < 7; ++kt) {
        f32x4 a0 = *(const f32x4*)(rowp + kt * 32);
        f32x4 a1 = *(const f32x4*)(rowp + kt * 32 + 4);
        bf16x8 Ahi, Alo;
#pragma unroll
        for (int j = 0; j < 4; ++j) {
            short hi = f2bf(a0[j]);
            Ahi[j] = hi;
            Alo[j] = f2bf(a0[j] - bf2f(hi));
        }
#pragma unroll
        for (int j = 0; j < 4; ++j) {
            short hi = f2bf(a1[j]);
            Ahi[4 + j] = hi;
            Alo[4 + j] = f2bf(a1[j] - bf2f(hi));
        }
#pragma unroll
        for (int nt = 0; nt < 4; ++nt) {
            const int boff = (nt * 16 + m) * 232 + kt * 32 + q * 8;
            bf16x8 Bh = *(const bf16x8*)&Whi[boff];
            bf16x8 Bl = *(const bf16x8*)&Wlo[boff];
            C[nt] = __builtin_amdgcn_mfma_f32_16x16x32_bf16(Ahi, Bh, C[nt], 0, 0, 0);
            C[nt] = __builtin_amdgcn_mfma_f32_16x16x32_bf16(Ahi, Bl, C[nt], 0, 0, 0);
            C[nt] = __builtin_amdgcn_mfma_f32_16x16x32_bf16(Alo, Bh, C[nt], 0, 0, 0);
        }
    }

    float wp2r[4], bp1r[4];
#pragma unroll
    for (int nt = 0; nt < 4; ++nt) {
        wp2r[nt] = Wp2[nt * 16 + m];
        bp1r[nt] = bp1[nt * 16 + m];
    }
    const float bp2v = bp2[0];
    float s[4];
#pragma unroll
    for (int r = 0; r < 4; ++r) {
        float acc = 0.0f;
#pragma unroll
        for (int nt = 0; nt < 4; ++nt)
            acc += fmaxf(C[nt][r] + bp1r[nt], 0.0f) * wp2r[nt];
        s[r] = acc;
    }
#pragma unroll
    for (int off = 1; off < 16; off <<= 1) {
#pragma unroll
        for (int r = 0; r < 4; ++r) s[r] += __shfl_xor(s[r], off);
    }
    if (m == 0) {
#pragma unroll
        for (int r = 0; r < 4; ++r) out[g0 + q * 4 + r] = s[r] + bp2v;
    }
}

extern "C" void kernel_launch(void* const* d_in, const int* in_sizes, int n_in,
                              void* d_out, int out_size, void* d_ws, size_t ws_size,
                              hipStream_t stream) {
    const int N = N_NODES, E = N_EDGES, G = N_GRAPHS;
    const int NT = N + G;

    const float* x        = (const float*)d_in[0];
    const float* metadata = (const float*)d_in[1];
    const int*   ei       = (const int*)d_in[2];
    const int*   batch    = (const int*)d_in[3];
    const int*   species  = (const int*)d_in[4];
    const float* W1 = (const float*)d_in[5];
    const float* b1 = (const float*)d_in[6];
    const float* W2 = (const float*)d_in[7];
    const float* b2 = (const float*)d_in[8];
    const float* W3 = (const float*)d_in[9];
    const float* b3 = (const float*)d_in[10];
    const float* Wm = (const float*)d_in[11];
    const float* bm = (const float*)d_in[12];
    const float* emb = (const float*)d_in[13];
    const float* Wp1 = (const float*)d_in[14];
    const float* bp1 = (const float*)d_in[15];
    const float* Wp2 = (const float*)d_in[16];
    const float* bp2 = (const float*)d_in[17];
    float* out = (float*)d_out;

    char* ws = (char*)d_ws;
    size_t off = 0;
    auto alloc = [&](size_t bytes) -> void* {
        void* p = ws + off;
        off = (off + bytes + 255) & ~(size_t)255;
        return p;
    };
    int*   cnt     = (int*)alloc((size_t)NT * 4);
    int*   row_ptr = (int*)alloc((size_t)(N + 1) * 4);
    int*   cursor  = (int*)alloc((size_t)N * 4);
    float* dinv    = (float*)alloc((size_t)N * 4);
    int*   gstart  = (int*)alloc((size_t)G * 4);
    int*   bsum    = (int*)alloc(2048 * 4);
    int*   boffs   = (int*)alloc(2048 * 4);
    int*   bcur    = (int*)alloc((size_t)NBKT * 4);
    int*   colsS   = (int*)alloc((size_t)E * 4);
    float* psum    = (float*)alloc((size_t)G * 64 * 4);
    float* pmax    = (float*)alloc((size_t)G * 64 * 4);
    float* hA      = (float*)alloc((size_t)N * 64 * 4);
    float* hB      = (float*)alloc((size_t)N * 64 * 4);
    float* fused   = (float*)alloc((size_t)G * 224 * 4);

    int* degcnt = cnt;
    int* gcnt = cnt + N;
    int2* tmp = (int2*)hA;        // aliases hA: dead until layer-1 GEMM writes it

    const int nbE = (E + 255) / 256;    // 6250
    const int nbT = (NT + 255) / 256;   // 1627

    hipMemsetAsync(cnt, 0, (size_t)NT * 4, stream);
    hipMemsetAsync(psum, 0, (size_t)G * 64 * 4, stream);
    hipMemsetAsync(pmax, 0, (size_t)G * 64 * 4, stream);

    k_hist<<<nbE, 256, 0, stream>>>(ei, batch, degcnt, gcnt, E, N);
    k_scan_blocksum<<<nbT, 256, 0, stream>>>(cnt, bsum, NT);
    k_scan_single<<<1, 256, 0, stream>>>(bsum, boffs, nbT);
    k_scan_final<<<nbT, 256, 0, stream>>>(cnt, boffs, row_ptr, cursor, dinv, gstart,
                                          bcur, NT, N, E);
    k_bin<<<(E + BIN_CHUNK - 1) / BIN_CHUNK, 256, 0, stream>>>(ei, ei + E, bcur, tmp, E);
    k_scat2<<<NBKT, 256, 0, stream>>>(tmp, row_ptr, cursor, colsS, N);

    const int nTiles = N / 16;          // 25000
    // layer 1: M1 = (Dinv x) @ W1 ; agg -> h1' = dinv*relu(z)
    k_gemm_mfma<32, true><<<1563, 256, 0, stream>>>(x, W1, dinv, hA, nTiles);
    k_agg_seg<0><<<3125, 256, 0, stream>>>(hA, b1, row_ptr, colsS, dinv, batch,
                                           hB, psum, pmax);
    // layer 2: M2 = h1' @ W2 ; agg -> h2'
    k_gemm_mfma<64, false><<<1563, 256, 0, stream>>>(hB, W2, dinv, hA, nTiles);
    k_agg_seg<0><<<3125, 256, 0, stream>>>(hA, b2, row_ptr, colsS, dinv, batch,
                                           hB, psum, pmax);
    // layer 3: M3 = h2' @ W3 ; agg+pool (atomics into psum/pmax)
    k_gemm_mfma<64, false><<<1563, 256, 0, stream>>>(hB, W3, dinv, hA, nTiles);
    k_agg_seg<1><<<3125, 256, 0, stream>>>(hA, b3, row_ptr, colsS, dinv, batch,
                                           hB, psum, pmax);

    k_asm<<<512, 256, 0, stream>>>(psum, pmax, gcnt, metadata, species, emb, Wm, bm,
                                   fused, G);
    k_pred_mfma<<<(G / 16 + 3) / 4, 256, 0, stream>>>(fused, Wp1, bp1, Wp2, bp2, out, G);
}

// Round 10
// 647.369 us; speedup vs baseline: 1.5057x; 1.0854x over previous
//
#include <hip/hip_runtime.h>
#include <hip/hip_bf16.h>

#define N_NODES 400000
#define N_EDGES 1600000
#define N_GRAPHS 16384
#define CHUNK 32
#define NCHUNK (N_NODES / CHUNK)   // 12500

#define BSHIFT 11
#define NBKT ((N_NODES + (1 << BSHIFT) - 1) >> BSHIFT)   // 196 row-buckets
#define BIN_CHUNK 4096

typedef __attribute__((ext_vector_type(8))) short bf16x8;
typedef __attribute__((ext_vector_type(4))) float f32x4;
typedef unsigned short bfu;

__device__ __forceinline__ float rlane(float x, int k) {
    return __int_as_float(__builtin_amdgcn_readlane(__float_as_int(x), k));
}
__device__ __forceinline__ int rlanei(int x, int k) {
    return __builtin_amdgcn_readlane(x, k);
}

__device__ __forceinline__ short f2bf(float x) {  // RNE float -> bf16 bits
    unsigned u = __float_as_uint(x);
    unsigned r = (u + 0x7fffu + ((u >> 16) & 1u)) >> 16;
    return (short)r;
}
__device__ __forceinline__ float bf2f(short b) {
    return __uint_as_float(((unsigned)(unsigned short)b) << 16);
}
__device__ __forceinline__ float bfu2f(bfu b) {
    return __uint_as_float(((unsigned)b) << 16);
}

// ---- fused histogram ----
__global__ void k_hist(const int* __restrict__ rows, const int* __restrict__ batch,
                       int* __restrict__ degcnt, int* __restrict__ gcnt, int E, int N) {
    int t = blockIdx.x * blockDim.x + threadIdx.x;
    if (t < E) atomicAdd(&degcnt[rows[t]], 1);
    if (t < N) atomicAdd(&gcnt[batch[t]], 1);
}

__global__ void k_scan_blocksum(const int* __restrict__ src, int* __restrict__ bsum, int n) {
    __shared__ int s[256];
    int t = threadIdx.x;
    int idx = blockIdx.x * 256 + t;
    int v = idx < n ? src[idx] : 0;
    s[t] = v; __syncthreads();
    for (int off = 128; off > 0; off >>= 1) {
        if (t < off) s[t] += s[t + off];
        __syncthreads();
    }
    if (t == 0) bsum[blockIdx.x] = s[0];
}

__global__ void k_scan_single(const int* __restrict__ src, int* __restrict__ dst, int n) {
    __shared__ int s[256];
    __shared__ int carry_s;
    int t = threadIdx.x;
    if (t == 0) carry_s = 0;
    __syncthreads();
    for (int base = 0; base < n; base += 256) {
        int idx = base + t;
        int v = idx < n ? src[idx] : 0;
        s[t] = v; __syncthreads();
        for (int off = 1; off < 256; off <<= 1) {
            int x = (t >= off) ? s[t - off] : 0;
            __syncthreads();
            s[t] += x;
            __syncthreads();
        }
        int incl = s[t];
        int carry = carry_s;
        if (idx < n) dst[idx] = carry + incl - v;
        __syncthreads();
        if (t == 255) carry_s = carry + incl;
        __syncthreads();
    }
}

__global__ void k_scan_final(const int* __restrict__ src, const int* __restrict__ boffs,
                             int* __restrict__ row_ptr, int* __restrict__ cursor,
                             float* __restrict__ dinv, int* __restrict__ gstart,
                             int* __restrict__ bcur, int n, int N, int E) {
    __shared__ int s[256];
    int t = threadIdx.x;
    int idx = blockIdx.x * 256 + t;
    int v = idx < n ? src[idx] : 0;
    s[t] = v; __syncthreads();
    for (int off = 1; off < 256; off <<= 1) {
        int x = (t >= off) ? s[t - off] : 0;
        __syncthreads();
        s[t] += x;
        __syncthreads();
    }
    if (idx < n) {
        int excl = boffs[blockIdx.x] + s[t] - v;
        if (idx < N) {
            row_ptr[idx] = excl;
            cursor[idx] = excl;
            dinv[idx] = rsqrtf((float)v + 1.0f);
            if ((idx & ((1 << BSHIFT) - 1)) == 0) bcur[idx >> BSHIFT] = excl;
        } else {
            if (idx == N) row_ptr[N] = E;
            gstart[idx - N] = excl - E;
        }
    }
}

// ---- scatter phase A ----
__global__ __launch_bounds__(256) void k_bin(const int* __restrict__ rows,
                                             const int* __restrict__ cols,
                                             int* __restrict__ bcur,
                                             int2* __restrict__ tmp, int E) {
    __shared__ int lcnt[NBKT];
    __shared__ int lbase[NBKT];
    const int t = threadIdx.x;
    const int e0 = blockIdx.x * BIN_CHUNK;
    for (int i = t; i < NBKT; i += 256) lcnt[i] = 0;
    __syncthreads();
    int r[16];
#pragma unroll
    for (int k = 0; k < 16; ++k) {
        int e = e0 + k * 256 + t;
        r[k] = (e < E) ? rows[e] : -1;
        if (r[k] >= 0) atomicAdd(&lcnt[r[k] >> BSHIFT], 1);
    }
    __syncthreads();
    for (int i = t; i < NBKT; i += 256) lbase[i] = atomicAdd(&bcur[i], lcnt[i]);
    __syncthreads();
    for (int i = t; i < NBKT; i += 256) lcnt[i] = 0;
    __syncthreads();
#pragma unroll
    for (int k = 0; k < 16; ++k) {
        int e = e0 + k * 256 + t;
        if (r[k] >= 0) {
            int b = r[k] >> BSHIFT;
            int p = lbase[b] + atomicAdd(&lcnt[b], 1);
            tmp[p] = make_int2(r[k], cols[e]);
        }
    }
}

// ---- scatter phase B ----
__global__ __launch_bounds__(256) void k_scat2(const int2* __restrict__ tmp,
                                               const int* __restrict__ row_ptr,
                                               int* __restrict__ cursor,
                                               int* __restrict__ colsOut, int N) {
    const int b = blockIdx.x;
    const int s = row_ptr[b << BSHIFT];
    const int endr = min((b + 1) << BSHIFT, N);
    const int tend = row_ptr[endr];
#pragma unroll 4
    for (int e = s + threadIdx.x; e < tend; e += 256) {
        int2 rc = tmp[e];
        int pos = atomicAdd(&cursor[rc.x], 1);
        colsOut[pos] = rc.y;
    }
}

// ---- MFMA GEMM (grid-stride over 16-node tiles), split-bf16 hi/lo.
// Writes M in bf16 (one rounding per layer; agg accumulates fp32).
template <int IN_D, bool PRESCALE>
__global__ __launch_bounds__(256, 4) void k_gemm_mfma(
        const float* __restrict__ in, const float* __restrict__ W,
        const float* __restrict__ dinv, bfu* __restrict__ out, int nTiles) {
    constexpr int KT = IN_D / 32;
    const int lane = threadIdx.x & 63;
    const int m = lane & 15;
    const int q = lane >> 4;

    bf16x8 Bhi[4][KT], Blo[4][KT];
#pragma unroll
    for (int nt = 0; nt < 4; ++nt) {
#pragma unroll
        for (int kt = 0; kt < KT; ++kt) {
#pragma unroll
            for (int j = 0; j < 8; ++j) {
                int k = kt * 32 + q * 8 + j;
                float w = W[k * 64 + nt * 16 + m];
                short hi = f2bf(w);
                Bhi[nt][kt][j] = hi;
                Blo[nt][kt][j] = f2bf(w - bf2f(hi));
            }
        }
    }

    const int wv = (blockIdx.x * 256 + threadIdx.x) >> 6;
    const int nwv = (gridDim.x * 256) >> 6;

    for (int tile = wv; tile < nTiles; tile += nwv) {
        const int node0 = tile * 16;
        const float dv = PRESCALE ? dinv[node0 + m] : 1.0f;
        const float* rowp = in + (size_t)(node0 + m) * IN_D + q * 8;

        bf16x8 Ahi[KT], Alo[KT];
#pragma unroll
        for (int kt = 0; kt < KT; ++kt) {
            f32x4 a0 = *(const f32x4*)(rowp + kt * 32);
            f32x4 a1 = *(const f32x4*)(rowp + kt * 32 + 4);
#pragma unroll
            for (int j = 0; j < 4; ++j) {
                float xx = PRESCALE ? dv * a0[j] : a0[j];
                short hi = f2bf(xx);
                Ahi[kt][j] = hi;
                Alo[kt][j] = f2bf(xx - bf2f(hi));
            }
#pragma unroll
            for (int j = 0; j < 4; ++j) {
                float xx = PRESCALE ? dv * a1[j] : a1[j];
                short hi = f2bf(xx);
                Ahi[kt][4 + j] = hi;
                Alo[kt][4 + j] = f2bf(xx - bf2f(hi));
            }
        }

        f32x4 C[4];
#pragma unroll
        for (int nt = 0; nt < 4; ++nt) C[nt] = (f32x4){0.f, 0.f, 0.f, 0.f};
#pragma unroll
        for (int nt = 0; nt < 4; ++nt) {
#pragma unroll
            for (int kt = 0; kt < KT; ++kt) {
                C[nt] = __builtin_amdgcn_mfma_f32_16x16x32_bf16(Ahi[kt], Bhi[nt][kt], C[nt], 0, 0, 0);
                C[nt] = __builtin_amdgcn_mfma_f32_16x16x32_bf16(Ahi[kt], Blo[nt][kt], C[nt], 0, 0, 0);
                C[nt] = __builtin_amdgcn_mfma_f32_16x16x32_bf16(Alo[kt], Bhi[nt][kt], C[nt], 0, 0, 0);
            }
        }

        bfu* op = out + (size_t)node0 * 64;
#pragma unroll
        for (int nt = 0; nt < 4; ++nt) {
#pragma unroll
            for (int r = 0; r < 4; ++r) {
                op[(size_t)(q * 4 + r) * 64 + nt * 16 + m] = (bfu)f2bf(C[nt][r]);
            }
        }
    }
}

// ==== segmented-stream aggregation over bf16 M rows ====
// POOL=0: out[i] = dinv[i] * relu(dinv[i]*(M_i + sum_j M_j) + b)   (fp32 out)
// POOL=1: h3 = relu(...) pooled per graph-run -> atomics into psum/pmax.
template <int POOL>
__global__ __launch_bounds__(256, 8) void k_agg_seg(
        const bfu* __restrict__ M, const float* __restrict__ bias,
        const int* __restrict__ row_ptr, const int* __restrict__ cols,
        const float* __restrict__ dinv, const int* __restrict__ batch,
        float* __restrict__ out, float* __restrict__ psum,
        float* __restrict__ pmax) {
    const int lane = threadIdx.x & 63;
    int wid = (blockIdx.x * blockDim.x + threadIdx.x) >> 6;
    wid = __builtin_amdgcn_readfirstlane(wid);
    const int nw = (gridDim.x * blockDim.x) >> 6;
    const float b = bias[lane];

    for (int c = wid; c < NCHUNK; c += nw) {
        const int i0 = c * CHUNK;
        const int rpn = row_ptr[i0 + min(lane, CHUNK - 1) + 1];
        const int S = row_ptr[i0];
        const int ne = rlanei(rpn, CHUNK - 1) - S;
        const float dvv = dinv[i0 + min(lane, CHUNK - 1)];
        const int bvv = POOL ? batch[i0 + min(lane, CHUNK - 1)] : 0;

        int node = 0;
        int bnd = rlanei(rpn, 0) - S;
        float acc = 0.0f;
        float selfA = bfu2f(M[(size_t)i0 * 64 + lane]);
        float selfB = bfu2f(M[(size_t)(i0 + 1) * 64 + lane]);
        float selfC = bfu2f(M[(size_t)(i0 + 2) * 64 + lane]);
        int gcur = POOL ? rlanei(bvv, 0) : 0;
        float rsum = 0.0f, rmax = 0.0f;

        auto flush = [&]() {
            if (POOL) {
                atomicAdd(&psum[(size_t)gcur * 64 + lane], rsum);
                atomicMax((int*)&pmax[(size_t)gcur * 64 + lane], __float_as_int(rmax));
            }
        };
        auto finalize = [&]() {
            const float d = rlane(dvv, node);
            const float h = fmaxf(fmaf(d, selfA + acc, b), 0.0f);
            if (POOL) {
                const int g = rlanei(bvv, node);
                if (g != gcur) { flush(); gcur = g; rsum = 0.0f; rmax = 0.0f; }
                rsum += h;
                rmax = fmaxf(rmax, h);
            } else {
                out[(size_t)(i0 + node) * 64 + lane] = d * h;
            }
            acc = 0.0f;
            selfA = selfB;
            selfB = selfC;
            if (node + 3 < CHUNK) selfC = bfu2f(M[(size_t)(i0 + node + 3) * 64 + lane]);
            ++node;
            if (node < CHUNK) bnd = rlanei(rpn, node) - S;
        };

        if (ne > 0) {
            int bidx = 0;
            int a0 = S + lane, a1 = S + 64 + lane;
            int colv0 = (a0 < S + ne) ? cols[a0] : 0;
            int colv1 = (a1 < S + ne) ? cols[a1] : 0;
            float vbuf[8];
#pragma unroll
            for (int k = 0; k < 8; ++k) {
                int e = min(k, ne - 1);
                int cc = rlanei(colv0, e);
                vbuf[k] = bfu2f(M[(size_t)cc * 64 + lane]);
            }

            int j = 0;
            while (j + 8 <= ne) {
#pragma unroll
                for (int k = 0; k < 8; ++k) {
                    const int jj = j + k;
                    if ((jj & 63) == 0 && jj != 0) {
                        colv0 = colv1;
                        ++bidx;
                        int ad = S + (bidx + 1) * 64 + lane;
                        colv1 = (ad < S + ne) ? cols[ad] : 0;
                    }
                    while (jj == bnd) finalize();
                    acc += vbuf[k];
                    int ec = min(jj + 8, ne - 1);
                    int src = ((ec >> 6) == bidx) ? colv0 : colv1;
                    int cc = rlanei(src, ec & 63);
                    vbuf[k] = bfu2f(M[(size_t)cc * 64 + lane]);
                }
                j += 8;
            }
            for (; j < ne; ++j) {
                while (j == bnd) finalize();
                acc += vbuf[j & 7];
            }
        }
        while (node < CHUNK) finalize();
        flush();
    }
}

// ---- assemble fused vector: [mean | max | relu(meta@Wm+bm) | emb | pad] ----
__global__ __launch_bounds__(256) void k_asm(
        const float* __restrict__ psum, const float* __restrict__ pmax,
        const int* __restrict__ gcnt, const float* __restrict__ metadata,
        const int* __restrict__ species, const float* __restrict__ emb,
        const float* __restrict__ Wm, const float* __restrict__ bm,
        float* __restrict__ fused, int G) {
    const int lane = threadIdx.x & 63;
    int wv = (blockIdx.x * blockDim.x + threadIdx.x) >> 6;
    const int nw = (gridDim.x * blockDim.x) >> 6;
    const float bmr = bm[lane];
    float wmr[16];
#pragma unroll
    for (int k = 0; k < 16; ++k) wmr[k] = Wm[k * 64 + lane];
    for (int g = wv; g < G; g += nw) {
        float gc = (float)gcnt[g];
        float mean = psum[(size_t)g * 64 + lane] / fmaxf(gc, 1.0f);
        float mx = pmax[(size_t)g * 64 + lane];
        float md = lane < 16 ? metadata[(size_t)g * 16 + lane] : 0.0f;
        float mval = bmr;
#pragma unroll
        for (int k = 0; k < 16; ++k) mval = fmaf(rlane(md, k), wmr[k], mval);
        mval = fmaxf(mval, 0.0f);
        const int sid = species[g];
        float* fr = fused + (size_t)g * 224;
        fr[lane] = mean;
        fr[64 + lane] = mx;
        fr[128 + lane] = mval;
        if (lane < 16) fr[192 + lane] = emb[(size_t)sid * 16 + lane];
        else if (lane < 32) fr[192 + lane] = 0.0f;
    }
}

// ---- MFMA predictor head ----
__global__ __launch_bounds__(256, 2) void k_pred_mfma(
        const float* __restrict__ fused, const float* __restrict__ Wp1,
        const float* __restrict__ bp1, const float* __restrict__ Wp2,
        const float* __restrict__ bp2, float* __restrict__ out, int G) {
    __shared__ __align__(16) short Whi[64 * 232];
    __shared__ __align__(16) short Wlo[64 * 232];
    const int t = threadIdx.x;
    for (int idx = t; idx < 64 * 232; idx += 256) {
        int n = idx / 232;
        int k = idx % 232;
        float w = (k < 208) ? Wp1[(size_t)k * 64 + n] : 0.0f;
        short hi = f2bf(w);
        Whi[n * 232 + k] = hi;
        Wlo[n * 232 + k] = f2bf(w - bf2f(hi));
    }
    __syncthreads();

    const int lane = t & 63;
    const int wave = t >> 6;
    const int m = lane & 15;
    const int q = lane >> 4;
    const int g0 = (blockIdx.x * 4 + wave) * 16;
    if (g0 >= G) return;

    const float* rowp = fused + (size_t)(g0 + m) * 224 + q * 8;

    f32x4 C[4];
#pragma unroll
    for (int nt = 0; nt < 4; ++nt) C[nt] = (f32x4){0.f, 0.f, 0.f, 0.f};

#pragma unroll
    for (int kt = 0; kt < 7; ++kt) {
        f32x4 a0 = *(const f32x4*)(rowp + kt * 32);
        f32x4 a1 = *(const f32x4*)(rowp + kt * 32 + 4);
        bf16x8 Ahi, Alo;
#pragma unroll
        for (int j = 0; j < 4; ++j) {
            short hi = f2bf(a0[j]);
            Ahi[j] = hi;
            Alo[j] = f2bf(a0[j] - bf2f(hi));
        }
#pragma unroll
        for (int j = 0; j < 4; ++j) {
            short hi = f2bf(a1[j]);
            Ahi[4 + j] = hi;
            Alo[4 + j] = f2bf(a1[j] - bf2f(hi));
        }
#pragma unroll
        for (int nt = 0; nt < 4; ++nt) {
            const int boff = (nt * 16 + m) * 232 + kt * 32 + q * 8;
            bf16x8 Bh = *(const bf16x8*)&Whi[boff];
            bf16x8 Bl = *(const bf16x8*)&Wlo[boff];
            C[nt] = __builtin_amdgcn_mfma_f32_16x16x32_bf16(Ahi, Bh, C[nt], 0, 0, 0);
            C[nt] = __builtin_amdgcn_mfma_f32_16x16x32_bf16(Ahi, Bl, C[nt], 0, 0, 0);
            C[nt] = __builtin_amdgcn_mfma_f32_16x16x32_bf16(Alo, Bh, C[nt], 0, 0, 0);
        }
    }

    float wp2r[4], bp1r[4];
#pragma unroll
    for (int nt = 0; nt < 4; ++nt) {
        wp2r[nt] = Wp2[nt * 16 + m];
        bp1r[nt] = bp1[nt * 16 + m];
    }
    const float bp2v = bp2[0];
    float s[4];
#pragma unroll
    for (int r = 0; r < 4; ++r) {
        float acc = 0.0f;
#pragma unroll
        for (int nt = 0; nt < 4; ++nt)
            acc += fmaxf(C[nt][r] + bp1r[nt], 0.0f) * wp2r[nt];
        s[r] = acc;
    }
#pragma unroll
    for (int off = 1; off < 16; off <<= 1) {
#pragma unroll
        for (int r = 0; r < 4; ++r) s[r] += __shfl_xor(s[r], off);
    }
    if (m == 0) {
#pragma unroll
        for (int r = 0; r < 4; ++r) out[g0 + q * 4 + r] = s[r] + bp2v;
    }
}

extern "C" void kernel_launch(void* const* d_in, const int* in_sizes, int n_in,
                              void* d_out, int out_size, void* d_ws, size_t ws_size,
                              hipStream_t stream) {
    const int N = N_NODES, E = N_EDGES, G = N_GRAPHS;
    const int NT = N + G;

    const float* x        = (const float*)d_in[0];
    const float* metadata = (const float*)d_in[1];
    const int*   ei       = (const int*)d_in[2];
    const int*   batch    = (const int*)d_in[3];
    const int*   species  = (const int*)d_in[4];
    const float* W1 = (const float*)d_in[5];
    const float* b1 = (const float*)d_in[6];
    const float* W2 = (const float*)d_in[7];
    const float* b2 = (const float*)d_in[8];
    const float* W3 = (const float*)d_in[9];
    const float* b3 = (const float*)d_in[10];
    const float* Wm = (const float*)d_in[11];
    const float* bm = (const float*)d_in[12];
    const float* emb = (const float*)d_in[13];
    const float* Wp1 = (const float*)d_in[14];
    const float* bp1 = (const float*)d_in[15];
    const float* Wp2 = (const float*)d_in[16];
    const float* bp2 = (const float*)d_in[17];
    float* out = (float*)d_out;

    char* ws = (char*)d_ws;
    size_t off = 0;
    auto alloc = [&](size_t bytes) -> void* {
        void* p = ws + off;
        off = (off + bytes + 255) & ~(size_t)255;
        return p;
    };
    int*   cnt     = (int*)alloc((size_t)NT * 4);
    int*   row_ptr = (int*)alloc((size_t)(N + 1) * 4);
    int*   cursor  = (int*)alloc((size_t)N * 4);
    float* dinv    = (float*)alloc((size_t)N * 4);
    int*   gstart  = (int*)alloc((size_t)G * 4);
    int*   bsum    = (int*)alloc(2048 * 4);
    int*   boffs   = (int*)alloc(2048 * 4);
    int*   bcur    = (int*)alloc((size_t)NBKT * 4);
    int*   colsS   = (int*)alloc((size_t)E * 4);
    float* psum    = (float*)alloc((size_t)G * 64 * 4);
    float* pmax    = (float*)alloc((size_t)G * 64 * 4);
    bfu*   Mb      = (bfu*)alloc((size_t)N * 64 * 2);    // bf16 GEMM output
    float* hf      = (float*)alloc((size_t)N * 64 * 4);  // fp32 h' (agg output)
    float* fused   = (float*)alloc((size_t)G * 224 * 4);

    int* degcnt = cnt;
    int* gcnt = cnt + N;
    int2* tmp = (int2*)hf;        // aliases hf: dead until first agg writes it

    const int nbE = (E + 255) / 256;    // 6250
    const int nbT = (NT + 255) / 256;   // 1627

    hipMemsetAsync(cnt, 0, (size_t)NT * 4, stream);
    hipMemsetAsync(psum, 0, (size_t)G * 64 * 4, stream);
    hipMemsetAsync(pmax, 0, (size_t)G * 64 * 4, stream);

    k_hist<<<nbE, 256, 0, stream>>>(ei, batch, degcnt, gcnt, E, N);
    k_scan_blocksum<<<nbT, 256, 0, stream>>>(cnt, bsum, NT);
    k_scan_single<<<1, 256, 0, stream>>>(bsum, boffs, nbT);
    k_scan_final<<<nbT, 256, 0, stream>>>(cnt, boffs, row_ptr, cursor, dinv, gstart,
                                          bcur, NT, N, E);
    k_bin<<<(E + BIN_CHUNK - 1) / BIN_CHUNK, 256, 0, stream>>>(ei, ei + E, bcur, tmp, E);
    k_scat2<<<NBKT, 256, 0, stream>>>(tmp, row_ptr, cursor, colsS, N);

    const int nTiles = N / 16;          // 25000
    // layer 1: M1 = (Dinv x) @ W1 (bf16) ; agg -> h1' = dinv*relu(z) (fp32)
    k_gemm_mfma<32, true><<<1563, 256, 0, stream>>>(x, W1, dinv, Mb, nTiles);
    k_agg_seg<0><<<3125, 256, 0, stream>>>(Mb, b1, row_ptr, colsS, dinv, batch,
                                           hf, psum, pmax);
    // layer 2
    k_gemm_mfma<64, false><<<1563, 256, 0, stream>>>(hf, W2, dinv, Mb, nTiles);
    k_agg_seg<0><<<3125, 256, 0, stream>>>(Mb, b2, row_ptr, colsS, dinv, batch,
                                           hf, psum, pmax);
    // layer 3: GEMM then agg+pool (atomics into psum/pmax)
    k_gemm_mfma<64, false><<<1563, 256, 0, stream>>>(hf, W3, dinv, Mb, nTiles);
    k_agg_seg<1><<<3125, 256, 0, stream>>>(Mb, b3, row_ptr, colsS, dinv, batch,
                                           hf, psum, pmax);

    k_asm<<<512, 256, 0, stream>>>(psum, pmax, gcnt, metadata, species, emb, Wm, bm,
                                   fused, G);
    k_pred_mfma<<<(G / 16 + 3) / 4, 256, 0, stream>>>(fused, Wp1, bp1, Wp2, bp2, out, G);
}

// Round 11
// 512.407 us; speedup vs baseline: 1.9023x; 1.2634x over previous
//
#include <hip/hip_runtime.h>
#include <hip/hip_bf16.h>

#define N_NODES 400000
#define N_EDGES 1600000
#define N_GRAPHS 16384
#define CHUNK 32
#define NCHUNK (N_NODES / CHUNK)   // 12500

#define BSHIFT 11
#define BKT_N (1 << BSHIFT)                               // 2048 rows per bucket
#define NBKT ((N_NODES + BKT_N - 1) >> BSHIFT)            // 196 row-buckets
#define BIN_CHUNK 4096

typedef __attribute__((ext_vector_type(8))) short bf16x8;
typedef __attribute__((ext_vector_type(4))) float f32x4;
typedef unsigned short bfu;

__device__ __forceinline__ float rlane(float x, int k) {
    return __int_as_float(__builtin_amdgcn_readlane(__float_as_int(x), k));
}
__device__ __forceinline__ int rlanei(int x, int k) {
    return __builtin_amdgcn_readlane(x, k);
}

__device__ __forceinline__ short f2bf(float x) {  // RNE float -> bf16 bits
    unsigned u = __float_as_uint(x);
    unsigned r = (u + 0x7fffu + ((u >> 16) & 1u)) >> 16;
    return (short)r;
}
__device__ __forceinline__ float bf2f(short b) {
    return __uint_as_float(((unsigned)(unsigned short)b) << 16);
}
__device__ __forceinline__ float bfu2f(bfu b) {
    return __uint_as_float(((unsigned)b) << 16);
}

// ---- bucket counts: LDS histogram, ~196 global atomics per block ----
__global__ __launch_bounds__(256) void k_bcnt(const int* __restrict__ rows,
                                              int* __restrict__ bkt, int E) {
    __shared__ int l[NBKT];
    const int t = threadIdx.x;
    for (int i = t; i < NBKT; i += 256) l[i] = 0;
    __syncthreads();
    const int e0 = blockIdx.x * BIN_CHUNK;
#pragma unroll
    for (int k = 0; k < 16; ++k) {
        int e = e0 + k * 256 + t;
        if (e < E) atomicAdd(&l[rows[e] >> BSHIFT], 1);
    }
    __syncthreads();
    for (int i = t; i < NBKT; i += 256)
        if (l[i]) atomicAdd(&bkt[i], l[i]);
}

// ---- single-block exclusive scan over NBKT bucket counts ----
__global__ void k_bscan(const int* __restrict__ bkt, int* __restrict__ bbase,
                        int* __restrict__ bcur) {
    __shared__ int s[256];
    const int t = threadIdx.x;
    int v = (t < NBKT) ? bkt[t] : 0;
    s[t] = v; __syncthreads();
    for (int off = 1; off < 256; off <<= 1) {
        int x = (t >= off) ? s[t - off] : 0;
        __syncthreads();
        s[t] += x;
        __syncthreads();
    }
    int excl = s[t] - v;
    if (t < NBKT) { bbase[t] = excl; bcur[t] = excl; }
    if (t == NBKT) bbase[NBKT] = excl;   // = E
}

// ---- bin edges by row-bucket (LDS-combined reservations) ----
__global__ __launch_bounds__(256) void k_bin(const int* __restrict__ rows,
                                             const int* __restrict__ cols,
                                             int* __restrict__ bcur,
                                             int2* __restrict__ tmp, int E) {
    __shared__ int lcnt[NBKT];
    __shared__ int lbase[NBKT];
    const int t = threadIdx.x;
    const int e0 = blockIdx.x * BIN_CHUNK;
    for (int i = t; i < NBKT; i += 256) lcnt[i] = 0;
    __syncthreads();
    int r[16];
#pragma unroll
    for (int k = 0; k < 16; ++k) {
        int e = e0 + k * 256 + t;
        r[k] = (e < E) ? rows[e] : -1;
        if (r[k] >= 0) atomicAdd(&lcnt[r[k] >> BSHIFT], 1);
    }
    __syncthreads();
    for (int i = t; i < NBKT; i += 256) lbase[i] = atomicAdd(&bcur[i], lcnt[i]);
    __syncthreads();
    for (int i = t; i < NBKT; i += 256) lcnt[i] = 0;
    __syncthreads();
#pragma unroll
    for (int k = 0; k < 16; ++k) {
        int e = e0 + k * 256 + t;
        if (r[k] >= 0) {
            int b = r[k] >> BSHIFT;
            int p = lbase[b] + atomicAdd(&lcnt[b], 1);
            tmp[p] = make_int2(r[k], cols[e]);
        }
    }
}

// ---- per-bucket CSR build: row_ptr + dinv + cols scatter, all block-local ----
__global__ __launch_bounds__(256) void k_csr(const int2* __restrict__ tmp,
                                             const int* __restrict__ bbase,
                                             int* __restrict__ row_ptr,
                                             float* __restrict__ dinv,
                                             int* __restrict__ colsOut,
                                             int N, int E) {
    __shared__ int lcnt[BKT_N];
    __shared__ int lofs[BKT_N];
    __shared__ int tsum[256];
    const int t = threadIdx.x;
    const int b = blockIdx.x;
    const int r0 = b << BSHIFT;
    const int S = bbase[b];
    const int T = bbase[b + 1];
    for (int i = t; i < BKT_N; i += 256) lcnt[i] = 0;
    __syncthreads();
    for (int e = S + t; e < T; e += 256) atomicAdd(&lcnt[tmp[e].x - r0], 1);
    __syncthreads();
    // block scan of 2048 counts: 8 sequential per thread + 256-thread scan
    const int base8 = t * 8;
    int vals[8];
    int run = 0;
#pragma unroll
    for (int k = 0; k < 8; ++k) { vals[k] = run; run += lcnt[base8 + k]; }
    tsum[t] = run;
    __syncthreads();
    for (int off = 1; off < 256; off <<= 1) {
        int x = (t >= off) ? tsum[t - off] : 0;
        __syncthreads();
        tsum[t] += x;
        __syncthreads();
    }
    const int texcl = tsum[t] - run;
#pragma unroll
    for (int k = 0; k < 8; ++k) lofs[base8 + k] = texcl + vals[k];
    __syncthreads();
    for (int i = t; i < BKT_N; i += 256) {
        int node = r0 + i;
        if (node < N) {
            row_ptr[node] = S + lofs[i];
            dinv[node] = rsqrtf((float)lcnt[i] + 1.0f);
        }
    }
    if (b == 0 && t == 0) row_ptr[N] = E;
    __syncthreads();
    // scatter cols; lofs doubles as LDS cursor
    for (int e = S + t; e < T; e += 256) {
        int2 rc = tmp[e];
        int pos = S + atomicAdd(&lofs[rc.x - r0], 1);
        colsOut[pos] = rc.y;
    }
}

// ---- gstart from sorted batch via boundary detection (no atomics) ----
__global__ void k_gb(const int* __restrict__ batch, int* __restrict__ gstart,
                     int N, int G) {
    int i = blockIdx.x * blockDim.x + threadIdx.x;
    if (i <= N) {
        int b = (i < N) ? batch[i] : G;
        int prev = (i == 0) ? -1 : batch[i - 1];
        for (int g = prev + 1; g <= b; ++g) gstart[g] = i;
    }
}

// ---- MFMA GEMM (grid-stride over 16-node tiles).
// ABF16=0: A fp32, split hi/lo (3 MFMAs per nt,kt), optional dinv prescale.
// ABF16=1: A already bf16 (2 MFMAs per nt,kt). Output always bf16.
template <int IN_D, bool PRESCALE, bool ABF16>
__global__ __launch_bounds__(256, 4) void k_gemm_mfma(
        const void* __restrict__ in_, const float* __restrict__ W,
        const float* __restrict__ dinv, bfu* __restrict__ out, int nTiles) {
    constexpr int KT = IN_D / 32;
    const int lane = threadIdx.x & 63;
    const int m = lane & 15;
    const int q = lane >> 4;

    bf16x8 Bhi[4][KT], Blo[4][KT];
#pragma unroll
    for (int nt = 0; nt < 4; ++nt) {
#pragma unroll
        for (int kt = 0; kt < KT; ++kt) {
#pragma unroll
            for (int j = 0; j < 8; ++j) {
                int k = kt * 32 + q * 8 + j;
                float w = W[k * 64 + nt * 16 + m];
                short hi = f2bf(w);
                Bhi[nt][kt][j] = hi;
                Blo[nt][kt][j] = f2bf(w - bf2f(hi));
            }
        }
    }

    const int wv = (blockIdx.x * 256 + threadIdx.x) >> 6;
    const int nwv = (gridDim.x * 256) >> 6;

    for (int tile = wv; tile < nTiles; tile += nwv) {
        const int node0 = tile * 16;
        f32x4 C[4];
#pragma unroll
        for (int nt = 0; nt < 4; ++nt) C[nt] = (f32x4){0.f, 0.f, 0.f, 0.f};

        if (ABF16) {
            const bfu* rowb = (const bfu*)in_ + (size_t)(node0 + m) * IN_D + q * 8;
            bf16x8 A[KT];
#pragma unroll
            for (int kt = 0; kt < KT; ++kt) A[kt] = *(const bf16x8*)(rowb + kt * 32);
#pragma unroll
            for (int nt = 0; nt < 4; ++nt) {
#pragma unroll
                for (int kt = 0; kt < KT; ++kt) {
                    C[nt] = __builtin_amdgcn_mfma_f32_16x16x32_bf16(A[kt], Bhi[nt][kt], C[nt], 0, 0, 0);
                    C[nt] = __builtin_amdgcn_mfma_f32_16x16x32_bf16(A[kt], Blo[nt][kt], C[nt], 0, 0, 0);
                }
            }
        } else {
            const float dv = PRESCALE ? dinv[node0 + m] : 1.0f;
            const float* rowp = (const float*)in_ + (size_t)(node0 + m) * IN_D + q * 8;
            bf16x8 Ahi[KT], Alo[KT];
#pragma unroll
            for (int kt = 0; kt < KT; ++kt) {
                f32x4 a0 = *(const f32x4*)(rowp + kt * 32);
                f32x4 a1 = *(const f32x4*)(rowp + kt * 32 + 4);
#pragma unroll
                for (int j = 0; j < 4; ++j) {
                    float xx = PRESCALE ? dv * a0[j] : a0[j];
                    short hi = f2bf(xx);
                    Ahi[kt][j] = hi;
                    Alo[kt][j] = f2bf(xx - bf2f(hi));
                }
#pragma unroll
                for (int j = 0; j < 4; ++j) {
                    float xx = PRESCALE ? dv * a1[j] : a1[j];
                    short hi = f2bf(xx);
                    Ahi[kt][4 + j] = hi;
                    Alo[kt][4 + j] = f2bf(xx - bf2f(hi));
                }
            }
#pragma unroll
            for (int nt = 0; nt < 4; ++nt) {
#pragma unroll
                for (int kt = 0; kt < KT; ++kt) {
                    C[nt] = __builtin_amdgcn_mfma_f32_16x16x32_bf16(Ahi[kt], Bhi[nt][kt], C[nt], 0, 0, 0);
                    C[nt] = __builtin_amdgcn_mfma_f32_16x16x32_bf16(Ahi[kt], Blo[nt][kt], C[nt], 0, 0, 0);
                    C[nt] = __builtin_amdgcn_mfma_f32_16x16x32_bf16(Alo[kt], Bhi[nt][kt], C[nt], 0, 0, 0);
                }
            }
        }

        bfu* op = out + (size_t)node0 * 64;
#pragma unroll
        for (int nt = 0; nt < 4; ++nt) {
#pragma unroll
            for (int r = 0; r < 4; ++r) {
                op[(size_t)(q * 4 + r) * 64 + nt * 16 + m] = (bfu)f2bf(C[nt][r]);
            }
        }
    }
}

// ==== segmented-stream aggregation over bf16 M rows ====
// POOL=0: out[i] = bf16( dinv[i] * relu(dinv[i]*(M_i + sum_j M_j) + b) )
// POOL=1: h3 = relu(...) pooled per graph-run -> atomics into psum/pmax.
template <int POOL>
__global__ __launch_bounds__(256, 8) void k_agg_seg(
        const bfu* __restrict__ M, const float* __restrict__ bias,
        const int* __restrict__ row_ptr, const int* __restrict__ cols,
        const float* __restrict__ dinv, const int* __restrict__ batch,
        bfu* __restrict__ out, float* __restrict__ psum,
        float* __restrict__ pmax) {
    const int lane = threadIdx.x & 63;
    int wid = (blockIdx.x * blockDim.x + threadIdx.x) >> 6;
    wid = __builtin_amdgcn_readfirstlane(wid);
    const int nw = (gridDim.x * blockDim.x) >> 6;
    const float b = bias[lane];

    for (int c = wid; c < NCHUNK; c += nw) {
        const int i0 = c * CHUNK;
        const int rpn = row_ptr[i0 + min(lane, CHUNK - 1) + 1];
        const int S = row_ptr[i0];
        const int ne = rlanei(rpn, CHUNK - 1) - S;
        const float dvv = dinv[i0 + min(lane, CHUNK - 1)];
        const int bvv = POOL ? batch[i0 + min(lane, CHUNK - 1)] : 0;

        int node = 0;
        int bnd = rlanei(rpn, 0) - S;
        float acc = 0.0f;
        float selfA = bfu2f(M[(size_t)i0 * 64 + lane]);
        float selfB = bfu2f(M[(size_t)(i0 + 1) * 64 + lane]);
        float selfC = bfu2f(M[(size_t)(i0 + 2) * 64 + lane]);
        int gcur = POOL ? rlanei(bvv, 0) : 0;
        float rsum = 0.0f, rmax = 0.0f;

        auto flush = [&]() {
            if (POOL) {
                atomicAdd(&psum[(size_t)gcur * 64 + lane], rsum);
                atomicMax((int*)&pmax[(size_t)gcur * 64 + lane], __float_as_int(rmax));
            }
        };
        auto finalize = [&]() {
            const float d = rlane(dvv, node);
            const float h = fmaxf(fmaf(d, selfA + acc, b), 0.0f);
            if (POOL) {
                const int g = rlanei(bvv, node);
                if (g != gcur) { flush(); gcur = g; rsum = 0.0f; rmax = 0.0f; }
                rsum += h;
                rmax = fmaxf(rmax, h);
            } else {
                out[(size_t)(i0 + node) * 64 + lane] = (bfu)f2bf(d * h);
            }
            acc = 0.0f;
            selfA = selfB;
            selfB = selfC;
            if (node + 3 < CHUNK) selfC = bfu2f(M[(size_t)(i0 + node + 3) * 64 + lane]);
            ++node;
            if (node < CHUNK) bnd = rlanei(rpn, node) - S;
        };

        if (ne > 0) {
            int bidx = 0;
            int a0 = S + lane, a1 = S + 64 + lane;
            int colv0 = (a0 < S + ne) ? cols[a0] : 0;
            int colv1 = (a1 < S + ne) ? cols[a1] : 0;
            float vbuf[8];
#pragma unroll
            for (int k = 0; k < 8; ++k) {
                int e = min(k, ne - 1);
                int cc = rlanei(colv0, e);
                vbuf[k] = bfu2f(M[(size_t)cc * 64 + lane]);
            }

            int j = 0;
            while (j + 8 <= ne) {
#pragma unroll
                for (int k = 0; k < 8; ++k) {
                    const int jj = j + k;
                    if ((jj & 63) == 0 && jj != 0) {
                        colv0 = colv1;
                        ++bidx;
                        int ad = S + (bidx + 1) * 64 + lane;
                        colv1 = (ad < S + ne) ? cols[ad] : 0;
                    }
                    while (jj == bnd) finalize();
                    acc += vbuf[k];
                    int ec = min(jj + 8, ne - 1);
                    int src = ((ec >> 6) == bidx) ? colv0 : colv1;
                    int cc = rlanei(src, ec & 63);
                    vbuf[k] = bfu2f(M[(size_t)cc * 64 + lane]);
                }
                j += 8;
            }
            for (; j < ne; ++j) {
                while (j == bnd) finalize();
                acc += vbuf[j & 7];
            }
        }
        while (node < CHUNK) finalize();
        flush();
    }
}

// ---- assemble fused vector: [mean | max | relu(meta@Wm+bm) | emb | pad] ----
__global__ __launch_bounds__(256) void k_asm(
        const float* __restrict__ psum, const float* __restrict__ pmax,
        const int* __restrict__ gstart, const float* __restrict__ metadata,
        const int* __restrict__ species, const float* __restrict__ emb,
        const float* __restrict__ Wm, const float* __restrict__ bm,
        float* __restrict__ fused, int G) {
    const int lane = threadIdx.x & 63;
    int wv = (blockIdx.x * blockDim.x + threadIdx.x) >> 6;
    const int nw = (gridDim.x * blockDim.x) >> 6;
    const float bmr = bm[lane];
    float wmr[16];
#pragma unroll
    for (int k = 0; k < 16; ++k) wmr[k] = Wm[k * 64 + lane];
    for (int g = wv; g < G; g += nw) {
        float gc = (float)(gstart[g + 1] - gstart[g]);
        float mean = psum[(size_t)g * 64 + lane] / fmaxf(gc, 1.0f);
        float mx = pmax[(size_t)g * 64 + lane];
        float md = lane < 16 ? metadata[(size_t)g * 16 + lane] : 0.0f;
        float mval = bmr;
#pragma unroll
        for (int k = 0; k < 16; ++k) mval = fmaf(rlane(md, k), wmr[k], mval);
        mval = fmaxf(mval, 0.0f);
        const int sid = species[g];
        float* fr = fused + (size_t)g * 224;
        fr[lane] = mean;
        fr[64 + lane] = mx;
        fr[128 + lane] = mval;
        if (lane < 16) fr[192 + lane] = emb[(size_t)sid * 16 + lane];
        else if (lane < 32) fr[192 + lane] = 0.0f;
    }
}

// ---- MFMA predictor head ----
__global__ __launch_bounds__(256, 2) void k_pred_mfma(
        const float* __restrict__ fused, const float* __restrict__ Wp1,
        const float* __restrict__ bp1, const float* __restrict__ Wp2,
        const float* __restrict__ bp2, float* __restrict__ out, int G) {
    __shared__ __align__(16) short Whi[64 * 232];
    __shared__ __align__(16) short Wlo[64 * 232];
    const int t = threadIdx.x;
    for (int idx = t; idx < 64 * 232; idx += 256) {
        int n = idx / 232;
        int k = idx % 232;
        float w = (k < 208) ? Wp1[(size_t)k * 64 + n] : 0.0f;
        short hi = f2bf(w);
        Whi[n * 232 + k] = hi;
        Wlo[n * 232 + k] = f2bf(w - bf2f(hi));
    }
    __syncthreads();

    const int lane = t & 63;
    const int wave = t >> 6;
    const int m = lane & 15;
    const int q = lane >> 4;
    const int g0 = (blockIdx.x * 4 + wave) * 16;
    if (g0 >= G) return;

    const float* rowp = fused + (size_t)(g0 + m) * 224 + q * 8;

    f32x4 C[4];
#pragma unroll
    for (int nt = 0; nt < 4; ++nt) C[nt] = (f32x4){0.f, 0.f, 0.f, 0.f};

#pragma unroll
    for (int kt = 0; kt < 7; ++kt) {
        f32x4 a0 = *(const f32x4*)(rowp + kt * 32);
        f32x4 a1 = *(const f32x4*)(rowp + kt * 32 + 4);
        bf16x8 Ahi, Alo;
#pragma unroll
        for (int j = 0; j < 4; ++j) {
            short hi = f2bf(a0[j]);
            Ahi[j] = hi;
            Alo[j] = f2bf(a0[j] - bf2f(hi));
        }
#pragma unroll
        for (int j = 0; j < 4; ++j) {
            short hi = f2bf(a1[j]);
            Ahi[4 + j] = hi;
            Alo[4 + j] = f2bf(a1[j] - bf2f(hi));
        }
#pragma unroll
        for (int nt = 0; nt < 4; ++nt) {
            const int boff = (nt * 16 + m) * 232 + kt * 32 + q * 8;
            bf16x8 Bh = *(const bf16x8*)&Whi[boff];
            bf16x8 Bl = *(const bf16x8*)&Wlo[boff];
            C[nt] = __builtin_amdgcn_mfma_f32_16x16x32_bf16(Ahi, Bh, C[nt], 0, 0, 0);
            C[nt] = __builtin_amdgcn_mfma_f32_16x16x32_bf16(Ahi, Bl, C[nt], 0, 0, 0);
            C[nt] = __builtin_amdgcn_mfma_f32_16x16x32_bf16(Alo, Bh, C[nt], 0, 0, 0);
        }
    }

    float wp2r[4], bp1r[4];
#pragma unroll
    for (int nt = 0; nt < 4; ++nt) {
        wp2r[nt] = Wp2[nt * 16 + m];
        bp1r[nt] = bp1[nt * 16 + m];
    }
    const float bp2v = bp2[0];
    float s[4];
#pragma unroll
    for (int r = 0; r < 4; ++r) {
        float acc = 0.0f;
#pragma unroll
        for (int nt = 0; nt < 4; ++nt)
            acc += fmaxf(C[nt][r] + bp1r[nt], 0.0f) * wp2r[nt];
        s[r] = acc;
    }
#pragma unroll
    for (int off = 1; off < 16; off <<= 1) {
#pragma unroll
        for (int r = 0; r < 4; ++r) s[r] += __shfl_xor(s[r], off);
    }
    if (m == 0) {
#pragma unroll
        for (int r = 0; r < 4; ++r) out[g0 + q * 4 + r] = s[r] + bp2v;
    }
}

extern "C" void kernel_launch(void* const* d_in, const int* in_sizes, int n_in,
                              void* d_out, int out_size, void* d_ws, size_t ws_size,
                              hipStream_t stream) {
    const int N = N_NODES, E = N_EDGES, G = N_GRAPHS;

    const float* x        = (const float*)d_in[0];
    const float* metadata = (const float*)d_in[1];
    const int*   ei       = (const int*)d_in[2];
    const int*   batch    = (const int*)d_in[3];
    const int*   species  = (const int*)d_in[4];
    const float* W1 = (const float*)d_in[5];
    const float* b1 = (const float*)d_in[6];
    const float* W2 = (const float*)d_in[7];
    const float* b2 = (const float*)d_in[8];
    const float* W3 = (const float*)d_in[9];
    const float* b3 = (const float*)d_in[10];
    const float* Wm = (const float*)d_in[11];
    const float* bm = (const float*)d_in[12];
    const float* emb = (const float*)d_in[13];
    const float* Wp1 = (const float*)d_in[14];
    const float* bp1 = (const float*)d_in[15];
    const float* Wp2 = (const float*)d_in[16];
    const float* bp2 = (const float*)d_in[17];
    float* out = (float*)d_out;

    char* ws = (char*)d_ws;
    size_t off = 0;
    auto alloc = [&](size_t bytes) -> void* {
        void* p = ws + off;
        off = (off + bytes + 255) & ~(size_t)255;
        return p;
    };
    int*   row_ptr = (int*)alloc((size_t)(N + 1) * 4);
    float* dinv    = (float*)alloc((size_t)N * 4);
    int*   gstart  = (int*)alloc((size_t)(G + 1) * 4);
    int*   bkt     = (int*)alloc((size_t)NBKT * 4);
    int*   bbase   = (int*)alloc((size_t)(NBKT + 1) * 4);
    int*   bcur    = (int*)alloc((size_t)NBKT * 4);
    int*   colsS   = (int*)alloc((size_t)E * 4);
    float* psum    = (float*)alloc((size_t)G * 64 * 4);
    float* pmax    = (float*)alloc((size_t)G * 64 * 4);
    bfu*   Mb      = (bfu*)alloc((size_t)N * 64 * 2);    // bf16 GEMM output
    bfu*   hb      = (bfu*)alloc((size_t)N * 64 * 2);    // bf16 h' (agg output)
    float* fused   = (float*)alloc((size_t)G * 224 * 4);

    int2* tmp = (int2*)Mb;        // aliases Mb: dead until layer-1 GEMM writes it

    const int nbBin = (E + BIN_CHUNK - 1) / BIN_CHUNK;   // 391

    hipMemsetAsync(bkt, 0, (size_t)NBKT * 4, stream);
    hipMemsetAsync(psum, 0, (size_t)G * 64 * 4, stream);
    hipMemsetAsync(pmax, 0, (size_t)G * 64 * 4, stream);

    k_bcnt<<<nbBin, 256, 0, stream>>>(ei, bkt, E);
    k_bscan<<<1, 256, 0, stream>>>(bkt, bbase, bcur);
    k_bin<<<nbBin, 256, 0, stream>>>(ei, ei + E, bcur, tmp, E);
    k_csr<<<NBKT, 256, 0, stream>>>(tmp, bbase, row_ptr, dinv, colsS, N, E);
    k_gb<<<(N + 256) / 256 + 1, 256, 0, stream>>>(batch, gstart, N, G);

    const int nTiles = N / 16;          // 25000
    // layer 1: M1 = (Dinv x) @ W1 (bf16) ; agg -> h1' bf16
    k_gemm_mfma<32, true, false><<<1563, 256, 0, stream>>>(x, W1, dinv, Mb, nTiles);
    k_agg_seg<0><<<3125, 256, 0, stream>>>(Mb, b1, row_ptr, colsS, dinv, batch,
                                           hb, psum, pmax);
    // layer 2 (A bf16)
    k_gemm_mfma<64, false, true><<<1563, 256, 0, stream>>>(hb, W2, dinv, Mb, nTiles);
    k_agg_seg<0><<<3125, 256, 0, stream>>>(Mb, b2, row_ptr, colsS, dinv, batch,
                                           hb, psum, pmax);
    // layer 3: GEMM (A bf16) then agg+pool (atomics into psum/pmax)
    k_gemm_mfma<64, false, true><<<1563, 256, 0, stream>>>(hb, W3, dinv, Mb, nTiles);
    k_agg_seg<1><<<3125, 256, 0, stream>>>(Mb, b3, row_ptr, colsS, dinv, batch,
                                           hb, psum, pmax);

    k_asm<<<512, 256, 0, stream>>>(psum, pmax, gstart, metadata, species, emb, Wm, bm,
                                   fused, G);
    k_pred_mfma<<<(G / 16 + 3) / 4, 256, 0, stream>>>(fused, Wp1, bp1, Wp2, bp2, out, G);
}